// Round 12
// baseline (12565.211 us; speedup 1.0000x reference)
//
#include <hip/hip_runtime.h>
#include <cstdint>

#define T_LEN 2048
#define NB    32
#define NROWS (NB*T_LEN)   // 65536
#define HH    200
#define G4    800
#define TB    256          // LSTM time-chunk (per dispatch)

typedef _Float16 f16;
typedef _Float16 f16x2 __attribute__((ext_vector_type(2)));
typedef _Float16 f16x8 __attribute__((ext_vector_type(8)));
typedef float   floatx4 __attribute__((ext_vector_type(4)));

#define GLD_LDS16(g, l) __builtin_amdgcn_global_load_lds( \
    (const __attribute__((address_space(1))) void*)(g), \
    (__attribute__((address_space(3))) void*)(l), 16, 0, 0)

static __device__ __forceinline__ unsigned short f2h(float x) {
  f16 h = (f16)x; return __builtin_bit_cast(unsigned short, h);
}
static __device__ __forceinline__ float sigm(float x) {
  return __builtin_amdgcn_rcpf(1.f + __expf(-x));
}
static __device__ __forceinline__ float tanh_fast(float x) {
  return 1.f - 2.f * __builtin_amdgcn_rcpf(__expf(2.f * x) + 1.f);
}

// ---------------- P/Q precompute: P[dt,co]=sum_ci relu(k1)k2, Q with relu(-k1)
__global__ void pq_kernel(const float* __restrict__ k1w, const float* __restrict__ k2w,
                          float* __restrict__ PQ) {
  int id = blockIdx.x * 256 + threadIdx.x;   // 1536 total
  int pq = id / 768;
  int rem = id % 768;
  int wdt = rem / 256;
  int co  = rem % 256;
  float acc = 0.f;
  for (int ci = 0; ci < 256; ++ci) {
    float k = k1w[ci];
    float kk = pq ? fmaxf(-k, 0.f) : fmaxf(k, 0.f);
    acc += kk * k2w[((size_t)wdt * 256 + ci) * 256 + co];
  }
  PQ[id] = acc;
}

// ---------------- f16 weight prep (B matrices stored TRANSPOSED: [n][k])
// K3T[co][ci] ; Wx2[dir][c][k] with permuted col c=4n+q (gate g=q*200+n) ;
// WhA: per-lane MFMA A-fragments of Wh^T, [dir][ct<56][lane<64][28 dwords]
//   (ct = 16-gate-col tile; dwords 4*kt..4*kt+3 = k-tile kt<7 of 16x16x32 frags,
//    K padded 200->224 with zeros; col-tiles ct>=50 are zero)  [R5-verified layout] ;
// bcat permuted, f-gate +1 folded.
__global__ void prep_kernel(const float* __restrict__ k3w,
                            const float* __restrict__ Wf, const float* __restrict__ bfv,
                            const float* __restrict__ Wb, const float* __restrict__ bbv,
                            unsigned short* __restrict__ K3h, unsigned short* __restrict__ Wx2,
                            unsigned short* __restrict__ WhA, float* __restrict__ bcat) {
  int id = blockIdx.x * 256 + threadIdx.x;
  if (id < 65536) {                      // K3T[co*256+ci] = k3w[ci*256+co]
    K3h[id] = f2h(k3w[(id & 255) * 256 + (id >> 8)]);
    return;
  }
  id -= 65536;
  if (id < 409600) {                     // Wx2[dir][c<800][k<256]
    int dirv = id / 204800;
    int r = id % 204800;
    int c = r >> 8, k = r & 255;
    int n = c >> 2, q = c & 3;
    int g = q * 200 + n;
    const float* W = dirv ? Wb : Wf;
    Wx2[id] = f2h(W[k * 800 + g]);
    return;
  }
  id -= 409600;
  if (id < 401408) {                     // WhA halves: 2*56*64*28*2
    int hi = id & 1;
    int d  = id >> 1;                    // dword index
    int r  = d % 28;
    int t2 = d / 28;
    int lane = t2 & 63;
    int t3 = t2 >> 6;
    int ct = t3 % 56;
    int dirv = t3 / 56;
    int row = lane & 15;
    int kg  = lane >> 4;
    int c = ct * 16 + row;
    float v = 0.f;
    if (c < 800) {
      int kt = r >> 2;                   // 0..6
      int k = kt * 32 + kg * 8 + (r & 3) * 2 + hi;
      if (k < 200) {
        int n = c >> 2, q = c & 3;
        int g = q * 200 + n;
        const float* W = dirv ? Wb : Wf;
        v = W[(256 + k) * 800 + g];
      }
    }
    WhA[id] = f2h(v);
    return;
  }
  id -= 401408;
  if (id < 1600) {                       // bcat[dir*800 + c] with same perm; +1 on f gate
    int dirv = id / 800;
    int c = id % 800;
    int n = c >> 2, q = c & 3;
    int g = q * 200 + n;
    bcat[id] = (dirv ? bbv : bfv)[g] + (q == 2 ? 1.f : 0.f);
  }
}

// ---------------- conv2 via rank-1 collapse (6 FMA/elem)
__global__ void conv2_kernel(const float* __restrict__ s, const float* __restrict__ PQ,
                             unsigned short* __restrict__ C2) {
  int row = blockIdx.x;
  int co  = threadIdx.x;
  int t = row & (T_LEN - 1);
  float s0 = s[row];
  float sm = (t > 0)         ? s[row - 1] : 0.f;
  float sp = (t < T_LEN - 1) ? s[row + 1] : 0.f;
  const float* P = PQ;
  const float* Q = PQ + 768;
  float acc = 0.f;
  float a, m;
  a = fmaxf(sm, 0.f); m = fmaxf(-sm, 0.f);
  acc += a * P[0*256+co] + m * Q[0*256+co];
  a = fmaxf(s0, 0.f); m = fmaxf(-s0, 0.f);
  acc += a * P[1*256+co] + m * Q[1*256+co];
  a = fmaxf(sp, 0.f); m = fmaxf(-sp, 0.f);
  acc += a * P[2*256+co] + m * Q[2*256+co];
  C2[(size_t)row * 256 + co] = f2h(fmaxf(acc, 0.f));
}

// ---------------- MFMA GEMM, K=256 fixed. B given TRANSPOSED [n][256].
// mode 0: direct rows; out = relu(acc) + relu(s*k1aw+k1ab)   (conv3+conv1a -> enc)
// mode 2: gathered rows (chain/time-chunk); out = acc + bcat[dir*800+col]
__global__ __launch_bounds__(256, 2) void gemm_kernel(
    const unsigned short* __restrict__ Ag, const unsigned short* __restrict__ Bg0,
    int N, int ntiles, int mode,
    unsigned short* __restrict__ Outp,
    const float* __restrict__ bias, const float* __restrict__ Sg,
    const float* __restrict__ k1aw, const float* __restrict__ k1ab,
    const int* __restrict__ lens, int t0)
{
  __shared__ __align__(16) unsigned short Bl[128*128]; // [n][k-phase], xor-swizzled 16B chunks
  __shared__ __align__(16) unsigned short Al[128*40];  // [m][k32], pad 40 halves
  __shared__ int rowsrc[128];
  int tid = threadIdx.x;
  int tm = blockIdx.x / ntiles, tn = blockIdx.x % ntiles;
  int col0 = tn * 128;
  int lane = tid & 63, wv = tid >> 6;
  int quad = lane >> 4, l16 = lane & 15;
  int wrow = (wv & 1) * 64, wcol = (wv >> 1) * 64;

  int dirv = 0;
  if (mode == 2) dirv = ((tm * 128) >> 8) >> 5;   // chain = m/TB ; dir = chain>>5
  const unsigned short* Bg = Bg0 + (size_t)dirv * 204800;

  if (tid < 128) {
    int r;
    if (mode == 2) {
      int m = tm * 128 + tid;
      int ch = m >> 8;              // TB=256
      int ls = m & 255;
      int b = ch & 31, dd = ch >> 5;
      int L = lens[b]; L = (L < 0) ? 0 : ((L > T_LEN) ? T_LEN : L);
      int t = t0 + ls;
      int src = dd ? (L - 1 - t) : t;
      src = (src < 0) ? 0 : ((src > T_LEN - 1) ? (T_LEN - 1) : src);
      r = b * T_LEN + src;
    } else {
      r = tm * 128 + tid;
    }
    rowsrc[tid] = r;
  }

  floatx4 acc[16];
  #pragma unroll
  for (int i = 0; i < 16; ++i) acc[i] = (floatx4){0.f,0.f,0.f,0.f};

  for (int ph = 0; ph < 2; ++ph) {
    __syncthreads();
    // stage B half-panel from BT: rows n in [col0,col0+128), k in [ph*128, +128)
    #pragma unroll
    for (int it = 0; it < 8; ++it) {
      int idx = it * 256 + tid;             // 2048 b128 chunks
      int n  = idx >> 4;                    // 0..127 local col
      int k8 = idx & 15;                    // 16B chunk within phase
      int nn = col0 + n;
      uint4 v = (uint4){0u,0u,0u,0u};
      if (nn < N) v = *(const uint4*)(Bg + (size_t)nn * 256 + ph * 128 + k8 * 8);
      *(uint4*)(&Bl[n * 128 + ((k8 ^ (n & 7)) * 8)]) = v;
    }
    for (int kb2 = 0; kb2 < 4; ++kb2) {
      int kb = ph * 4 + kb2;
      __syncthreads();
      #pragma unroll
      for (int i = 0; i < 2; ++i) {
        int c2 = i * 256 + tid;
        int r = c2 >> 2, kc = (c2 & 3) * 8;
        uint4 v = *(const uint4*)(Ag + (size_t)rowsrc[r] * 256 + kb * 32 + kc);
        *(uint4*)(&Al[r * 40 + kc]) = v;
      }
      __syncthreads();
      f16x8 af[4], bfr[4];
      #pragma unroll
      for (int mt = 0; mt < 4; ++mt)
        af[mt] = *(const f16x8*)(&Al[(wrow + mt*16 + l16) * 40 + quad * 8]);
      #pragma unroll
      for (int nt = 0; nt < 4; ++nt) {
        int nl = wcol + nt*16 + l16;
        int c = kb2 * 4 + quad;
        bfr[nt] = *(const f16x8*)(&Bl[nl * 128 + ((c ^ (nl & 7)) * 8)]);
      }
      #pragma unroll
      for (int mt = 0; mt < 4; ++mt)
        #pragma unroll
        for (int nt = 0; nt < 4; ++nt)
          acc[mt*4+nt] = __builtin_amdgcn_mfma_f32_16x16x32_f16(af[mt], bfr[nt], acc[mt*4+nt], 0, 0, 0);
    }
  }
  #pragma unroll
  for (int mt = 0; mt < 4; ++mt) {
    #pragma unroll
    for (int nt = 0; nt < 4; ++nt) {
      floatx4 v = acc[mt*4+nt];
      int col = col0 + wcol + nt*16 + l16;
      if (col < N) {
        #pragma unroll
        for (int r = 0; r < 4; ++r) {
          int row = tm * 128 + wrow + mt*16 + quad*4 + r;
          float x = v[r];
          float o;
          if (mode == 0) {
            float sv = Sg[row];
            float a1 = sv * k1aw[col] + k1ab[col];
            o = fmaxf(x, 0.f) + fmaxf(a1, 0.f);
          } else {
            o = x + bias[dirv * 800 + col];
          }
          Outp[(size_t)row * N + col] = f2h(o);
        }
      }
    }
  }
}

// ---------------- consolidated MFMA recurrent LSTM: 4 WGs, 16 chains per WG.
// z[800 x 16chains] = Wh^T[800x200] @ H[200x16] per step: B's 16 cols = 16 chains' h.
// 8 waves x 512 thr; wave w owns col-tiles t = i*8+w (i<7; 56 padded, 50 real).
// A-frags (R5-verified WhA layout) persist in AGPRs -> MFMA reads them NATIVELY,
// eliminating the per-step AGPR<->VGPR shuttle that pinned every prior design at
// ~2550 cyc/step. D is activation-local: lane (quad,l16) holds all 4 gates (c=4n+q)
// of unit n=4t+quad for chain l16 -> no z exchange, ONE barrier per step.
// h in LDS [2][16][228] (stride 228 halves: bank-spread 2x ds_read_b64 B-frags).
// x staged per step via global_load_lds dbuf; h history in 8-slot ring, flushed
// coalesced every 4 steps (slot X%8 vs flush (X-4..X-1)%8 disjoint).
__global__ __launch_bounds__(512, 1)
void lstm_kernel(
    const unsigned short* __restrict__ XWbuf,  // [64][TB][800] f16, cols c=4n+q, bias(+1 f) folded
    const unsigned short* __restrict__ WhA,    // per-lane A-fragments (see prep)
    const int* __restrict__ lens,
    unsigned short* __restrict__ fwH, unsigned short* __restrict__ bwH,
    float* __restrict__ cState, unsigned short* __restrict__ hState,
    int t0)
{
  int g    = blockIdx.x;          // 0..3
  int dir  = g >> 1;
  int sbase = (g & 1) * 16;
  int tid  = threadIdx.x;
  int lane = tid & 63, w = tid >> 6;   // 8 waves
  int qd   = lane >> 4;                // k-group / D-row quad
  int cc   = lane & 15;                // chain column

  __shared__ __align__(16) unsigned short xw[2][16*800];    // 51.2 KB
  __shared__ __align__(16) unsigned short hist[8][16*200];  // 51.2 KB
  __shared__ __align__(16) unsigned short himg[2*16*228];   // 14.6 KB
  __shared__ int lensl[16];

  if (tid < 16) {
    int Lv = lens[sbase + tid];
    lensl[tid] = (Lv < 0) ? 0 : ((Lv > T_LEN) ? T_LEN : Lv);
  }
  for (int i = tid; i < 3648; i += 512) ((unsigned int*)himg)[i] = 0u;
  __syncthreads();
  if (t0 > 0) {
    for (int idx = tid; idx < 3200; idx += 512) {
      int c = idx / 200, n = idx % 200;
      unsigned short hv = hState[((dir * 32 + sbase + c)) * HH + n];
      himg[c * 228 + n] = hv;
      himg[3648 + c * 228 + n] = hv;
    }
  }
  int Lc = lensl[cc];
  int ch_lane = dir * 32 + sbase + cc;

  // per-lane c-state for tiles t = i*8+w (unit n = 4t+qd), t<50 real
  float cst[7];
  #pragma unroll
  for (int i = 0; i < 7; ++i) cst[i] = 0.f;
  if (t0 > 0) {
    #pragma unroll
    for (int i = 0; i < 7; ++i) {
      int t = i * 8 + w;
      if (t < 50) cst[i] = cState[ch_lane * HH + 4 * t + qd];
    }
  }

  // persistent A-fragments (7 tiles/wave, 7 k-tiles each) -> AGPR-resident
  f16x8 WA[7][7];
  #pragma unroll
  for (int i = 0; i < 7; ++i) {
    int ct = i * 8 + w;
    const uint4* wp = (const uint4*)WhA + ((size_t)((dir * 56 + ct) * 64 + lane)) * 7;
    #pragma unroll
    for (int kt = 0; kt < 7; ++kt)
      WA[i][kt] = __builtin_bit_cast(f16x8, wp[kt]);
  }

  unsigned short* Hd = dir ? bwH : fwH;

  // stage step 0
  #pragma unroll
  for (int it = 0; it < 4; ++it) {
    int cidx = it * 512 + tid;
    if (cidx < 1600) {
      int c = cidx / 100, off = cidx % 100;
      const unsigned short* src = XWbuf + ((size_t)(dir * 32 + sbase + c) * TB + 0) * 800 + off * 8;
      GLD_LDS16(src, &xw[0][cidx * 8]);
    }
  }
  __syncthreads();   // h-state visible; step-0 DMA drained

  int cur = 0, buf = 0;

  for (int sl = 0; sl < TB; ++sl) {
    int tgl = t0 + sl;
    // prefetch next step's x
    if (sl + 1 < TB) {
      #pragma unroll
      for (int it = 0; it < 4; ++it) {
        int cidx = it * 512 + tid;
        if (cidx < 1600) {
          int c = cidx / 100, off = cidx % 100;
          const unsigned short* src = XWbuf + ((size_t)(dir * 32 + sbase + c) * TB + (sl + 1)) * 800 + off * 8;
          GLD_LDS16(src, &xw[buf ^ 1][cidx * 8]);
        }
      }
    }
    // coalesced flush of previous 4 steps' h (slots disjoint from this step's write)
    if ((sl & 3) == 0 && sl > 0) {
      #pragma unroll
      for (int it = 0; it < 4; ++it) {
        int idx = it * 512 + tid;
        if (idx < 1600) {
          int j = idx / 400;
          int r = idx % 400;
          int c = r / 25, seg = r % 25;
          int slot = (sl - 4 + j) & 7;
          int ts = t0 + sl - 4 + j;
          int Lc2 = lensl[c];
          uint4 v = *(const uint4*)&hist[slot][c * 200 + seg * 8];
          int bi = sbase + c;
          if (dir == 0) {
            *(uint4*)(Hd + ((size_t)(bi * T_LEN + ts)) * HH + seg * 8) = v;
          } else if (ts < Lc2) {
            *(uint4*)(Hd + ((size_t)(bi * T_LEN + (Lc2 - 1 - ts))) * HH + seg * 8) = v;
          }
        }
      }
    }
    // B-frags + MFMA (kt-outer to keep only one B-frag live)
    floatx4 C[7];
    #pragma unroll
    for (int i = 0; i < 7; ++i) C[i] = (floatx4){0.f,0.f,0.f,0.f};
    #pragma unroll
    for (int kt = 0; kt < 7; ++kt) {
      int ha = cur * 3648 + cc * 228 + kt * 32 + qd * 8;
      uint2 lo = *(const uint2*)&himg[ha];
      uint2 hi = *(const uint2*)&himg[ha + 4];
      uint4 bb; bb.x = lo.x; bb.y = lo.y; bb.z = hi.x; bb.w = hi.y;
      f16x8 bf = __builtin_bit_cast(f16x8, bb);
      #pragma unroll
      for (int i = 0; i < 7; ++i)
        C[i] = __builtin_amdgcn_mfma_f32_16x16x32_f16(WA[i][kt], bf, C[i], 0, 0, 0);
    }
    // activation: lane-local (all 4 gates of unit 4t+qd, chain cc)
    bool live = tgl < Lc;
    #pragma unroll
    for (int i = 0; i < 7; ++i) {
      int t = i * 8 + w;
      if (t < 50) {
        int n = 4 * t + qd;
        uint2 xv = *(const uint2*)&xw[buf][cc * 800 + 4 * n];
        f16x2 xa = __builtin_bit_cast(f16x2, xv.x);
        f16x2 xb = __builtin_bit_cast(f16x2, xv.y);
        float zi = C[i][0] + (float)xa[0];
        float zj = C[i][1] + (float)xa[1];
        float zf = C[i][2] + (float)xb[0];
        float zo = C[i][3] + (float)xb[1];
        float cn = cst[i] * sigm(zf) + sigm(zi) * tanh_fast(zj);
        float h  = tanh_fast(cn) * sigm(zo);
        unsigned short hh = f2h(h);
        if (live) {
          cst[i] = cn;
          himg[(cur ^ 1) * 3648 + cc * 228 + n] = hh;
        }
        hist[sl & 7][cc * 200 + n] = live ? hh : (unsigned short)0;
      }
    }
    cur ^= 1; buf ^= 1;
    __syncthreads();   // h/hist visible; prefetch DMA drained for next step
  }
  // final flush: steps TB-4..TB-1
  {
    #pragma unroll
    for (int it = 0; it < 4; ++it) {
      int idx = it * 512 + tid;
      if (idx < 1600) {
        int j = idx / 400;
        int r = idx % 400;
        int c = r / 25, seg = r % 25;
        int slot = (TB - 4 + j) & 7;
        int ts = t0 + TB - 4 + j;
        int Lc2 = lensl[c];
        uint4 v = *(const uint4*)&hist[slot][c * 200 + seg * 8];
        int bi = sbase + c;
        if (dir == 0) {
          *(uint4*)(Hd + ((size_t)(bi * T_LEN + ts)) * HH + seg * 8) = v;
        } else if (ts < Lc2) {
          *(uint4*)(Hd + ((size_t)(bi * T_LEN + (Lc2 - 1 - ts))) * HH + seg * 8) = v;
        }
      }
    }
  }
  // state save
  #pragma unroll
  for (int i = 0; i < 7; ++i) {
    int t = i * 8 + w;
    if (t < 50) cState[ch_lane * HH + 4 * t + qd] = cst[i];
  }
  for (int idx = tid; idx < 3200; idx += 512) {
    int c = idx / 200, n = idx % 200;
    hState[(dir * 32 + sbase + c) * HH + n] = himg[cur * 3648 + c * 228 + n];
  }
}

// ---------------- logits = [fwH|bwH] @ Wd + bd
__global__ __launch_bounds__(256) void out_kernel(
    const unsigned short* __restrict__ fwH, const unsigned short* __restrict__ bwH,
    const float* __restrict__ Wd, const float* __restrict__ bd, float* __restrict__ out)
{
  __shared__ float wd[2000];
  int tid = threadIdx.x;
  for (int i = tid; i < 2000; i += 256) wd[i] = Wd[i];
  __syncthreads();
  int row = blockIdx.x * 256 + tid;
  float acc0 = bd[0], acc1 = bd[1], acc2 = bd[2], acc3 = bd[3], acc4 = bd[4];
  const unsigned int* fu = (const unsigned int*)(fwH + (size_t)row * HH);
  const unsigned int* bu = (const unsigned int*)(bwH + (size_t)row * HH);
  #pragma unroll 4
  for (int i = 0; i < 100; ++i) {
    f16x2 pf = __builtin_bit_cast(f16x2, fu[i]);
    f16x2 pb = __builtin_bit_cast(f16x2, bu[i]);
    int k = 2 * i;
    float f0 = (float)pf[0], f1 = (float)pf[1];
    float b0 = (float)pb[0], b1 = (float)pb[1];
    const float* w0 = &wd[k*5];
    const float* w1 = &wd[(k+1)*5];
    const float* w2 = &wd[(200+k)*5];
    const float* w3 = &wd[(201+k)*5];
    acc0 += f0*w0[0] + f1*w1[0] + b0*w2[0] + b1*w3[0];
    acc1 += f0*w0[1] + f1*w1[1] + b0*w2[1] + b1*w3[1];
    acc2 += f0*w0[2] + f1*w1[2] + b0*w2[2] + b1*w3[2];
    acc3 += f0*w0[3] + f1*w1[3] + b0*w2[3] + b1*w3[3];
    acc4 += f0*w0[4] + f1*w1[4] + b0*w2[4] + b1*w3[4];
  }
  float* o = out + (size_t)row * 5;
  o[0]=acc0; o[1]=acc1; o[2]=acc2; o[3]=acc3; o[4]=acc4;
}

extern "C" void kernel_launch(void* const* d_in, const int* in_sizes, int n_in,
                              void* d_out, int out_size, void* d_ws, size_t ws_size,
                              hipStream_t stream)
{
  const float* signals = (const float*)d_in[0];
  const int*   lens    = (const int*)  d_in[1];
  const float* k1w     = (const float*)d_in[2];
  const float* k1aw    = (const float*)d_in[3];
  const float* k1ab    = (const float*)d_in[4];
  const float* k2w     = (const float*)d_in[5];
  const float* k3w     = (const float*)d_in[6];
  const float* Wf      = (const float*)d_in[7];
  const float* bf      = (const float*)d_in[8];
  const float* Wb      = (const float*)d_in[9];
  const float* bb      = (const float*)d_in[10];
  const float* Wd      = (const float*)d_in[11];
  const float* bd      = (const float*)d_in[12];
  float* out = (float*)d_out;
  char* ws = (char*)d_ws;

  // Region A aliases C2 (conv phase) and XWbuf (LSTM phase) — disjoint lifetimes.
  size_t szC2   = (size_t)NROWS * 256 * 2;          // 33,554,432
  size_t szXWb  = (size_t)64 * TB * 800 * 2;        // 26,214,400
  size_t szA    = (szC2 > szXWb) ? szC2 : szXWb;
  size_t oA   = 0;
  size_t oE   = oA   + szA;
  size_t oFw  = oE   + (size_t)NROWS*256*2;
  size_t oBw  = oFw  + (size_t)NROWS*HH*2;
  size_t oWhA = oBw  + (size_t)NROWS*HH*2;
  size_t oWx2 = oWhA + (size_t)2*56*64*28*4;        // 802,816
  size_t oK3  = oWx2 + (size_t)2*256*800*2;
  size_t oPQ  = oK3  + (size_t)256*256*2;
  size_t oBc  = oPQ  + 1536*4;
  size_t oCst = oBc  + 1600*4;
  size_t oHst = oCst + (size_t)64*HH*4;
  size_t total= oHst + (size_t)64*HH*2;
  if (ws_size < total) return;

  unsigned short* C2    = (unsigned short*)(ws + oA);
  unsigned short* XWbuf = (unsigned short*)(ws + oA);
  unsigned short* E     = (unsigned short*)(ws + oE);
  unsigned short* fwH   = (unsigned short*)(ws + oFw);
  unsigned short* bwH   = (unsigned short*)(ws + oBw);
  unsigned short* WhA   = (unsigned short*)(ws + oWhA);
  unsigned short* Wx2   = (unsigned short*)(ws + oWx2);
  unsigned short* K3h   = (unsigned short*)(ws + oK3);
  float* PQ     = (float*)(ws + oPQ);
  float* bcat   = (float*)(ws + oBc);
  float* cState = (float*)(ws + oCst);
  unsigned short* hState = (unsigned short*)(ws + oHst);

  (void)hipMemsetAsync(fwH, 0, (size_t)2*NROWS*HH*2, stream);
  pq_kernel  <<<6,     256, 0, stream>>>(k1w, k2w, PQ);
  prep_kernel<<<3431,  256, 0, stream>>>(k3w, Wf, bf, Wb, bb, K3h, Wx2, WhA, bcat);
  conv2_kernel<<<NROWS, 256, 0, stream>>>(signals, PQ, C2);
  gemm_kernel<<<1024,  256, 0, stream>>>(C2, K3h, 256, 2, 0, E, nullptr, signals, k1aw, k1ab, nullptr, 0);
  for (int t0 = 0; t0 < T_LEN; t0 += TB) {
    gemm_kernel<<<896, 256, 0, stream>>>(E, Wx2, 800, 7, 2, XWbuf, bcat, nullptr, nullptr, nullptr, lens, t0);
    lstm_kernel<<<4,   512, 0, stream>>>(XWbuf, WhA, lens, fwH, bwH, cState, hState, t0);
  }
  out_kernel <<<256,   256, 0, stream>>>(fwH, bwH, Wd, bd, out);
}

// Round 13
// 2573.456 us; speedup vs baseline: 4.8826x; 4.8826x over previous
//
#include <hip/hip_runtime.h>
#include <cstdint>

#define T_LEN 2048
#define NB    32
#define NROWS (NB*T_LEN)   // 65536
#define HH    200
#define G4    800
#define TB    256          // LSTM time-chunk (per dispatch)
#define SB    8            // step block staged in LDS

typedef _Float16 f16;
typedef _Float16 f16x2 __attribute__((ext_vector_type(2)));
typedef _Float16 f16x8 __attribute__((ext_vector_type(8)));
typedef float   floatx4 __attribute__((ext_vector_type(4)));

#define GLD_LDS16(g, l) __builtin_amdgcn_global_load_lds( \
    (const __attribute__((address_space(1))) void*)(g), \
    (__attribute__((address_space(3))) void*)(l), 16, 0, 0)

static __device__ __forceinline__ unsigned short f2h(float x) {
  f16 h = (f16)x; return __builtin_bit_cast(unsigned short, h);
}
static __device__ __forceinline__ float dot2f(unsigned int a, unsigned int b, float c) {
  return __builtin_amdgcn_fdot2(__builtin_bit_cast(f16x2, a),
                                __builtin_bit_cast(f16x2, b), c, false);
}
static __device__ __forceinline__ float sigm(float x) {
  return __builtin_amdgcn_rcpf(1.f + __expf(-x));
}
static __device__ __forceinline__ float tanh_fast(float x) {
  return 1.f - 2.f * __builtin_amdgcn_rcpf(__expf(2.f * x) + 1.f);
}

// ---------------- P/Q precompute: P[dt,co]=sum_ci relu(k1)k2, Q with relu(-k1)
__global__ void pq_kernel(const float* __restrict__ k1w, const float* __restrict__ k2w,
                          float* __restrict__ PQ) {
  int id = blockIdx.x * 256 + threadIdx.x;   // 1536 total
  int pq = id / 768;
  int rem = id % 768;
  int wdt = rem / 256;
  int co  = rem % 256;
  float acc = 0.f;
  for (int ci = 0; ci < 256; ++ci) {
    float k = k1w[ci];
    float kk = pq ? fmaxf(-k, 0.f) : fmaxf(k, 0.f);
    acc += kk * k2w[((size_t)wdt * 256 + ci) * 256 + co];
  }
  PQ[id] = acc;
}

// ---------------- f16 weight prep (B matrices stored TRANSPOSED: [n][k])
// K3T[co][ci] ; Wx2[dir][c][k] with permuted col c=4n+q (gate g=q*200+n) ;
// WhK: per-thread 5-way k-chunk weight records [dir][s<5][n<200][4 gates][40 halves]
//   (record = 160 halves = 80 dwords; half j of gate q = W[256 + s*40 + j][g]; 5x40=200,
//    no padding) ;
// bcat permuted, f-gate +1 folded.
__global__ void prep_kernel(const float* __restrict__ k3w,
                            const float* __restrict__ Wf, const float* __restrict__ bfv,
                            const float* __restrict__ Wb, const float* __restrict__ bbv,
                            unsigned short* __restrict__ K3h, unsigned short* __restrict__ Wx2,
                            unsigned short* __restrict__ WhK, float* __restrict__ bcat) {
  int id = blockIdx.x * 256 + threadIdx.x;
  if (id < 65536) {                      // K3T[co*256+ci] = k3w[ci*256+co]
    K3h[id] = f2h(k3w[(id & 255) * 256 + (id >> 8)]);
    return;
  }
  id -= 65536;
  if (id < 409600) {                     // Wx2[dir][c<800][k<256]
    int dirv = id / 204800;
    int r = id % 204800;
    int c = r >> 8, k = r & 255;
    int n = c >> 2, q = c & 3;
    int g = q * 200 + n;
    const float* W = dirv ? Wb : Wf;
    Wx2[id] = f2h(W[k * 800 + g]);
    return;
  }
  id -= 409600;
  if (id < 320000) {                     // WhK halves: 2*5*200*160
    int rec = id / 160;
    int m   = id % 160;
    int g   = m / 40, j = m % 40;
    int n   = rec % 200;
    int t2  = rec / 200;                 // 0..9
    int s   = t2 % 5, dirv = t2 / 5;
    int k   = s * 40 + j;
    const float* W = dirv ? Wb : Wf;
    WhK[id] = f2h(W[(256 + k) * 800 + (g * 200 + n)]);
    return;
  }
  id -= 320000;
  if (id < 1600) {                       // bcat[dir*800 + c] with same perm; +1 on f gate
    int dirv = id / 800;
    int c = id % 800;
    int n = c >> 2, q = c & 3;
    int g = q * 200 + n;
    bcat[id] = (dirv ? bbv : bfv)[g] + (q == 2 ? 1.f : 0.f);
  }
}

// ---------------- conv2 via rank-1 collapse (6 FMA/elem)
__global__ void conv2_kernel(const float* __restrict__ s, const float* __restrict__ PQ,
                             unsigned short* __restrict__ C2) {
  int row = blockIdx.x;
  int co  = threadIdx.x;
  int t = row & (T_LEN - 1);
  float s0 = s[row];
  float sm = (t > 0)         ? s[row - 1] : 0.f;
  float sp = (t < T_LEN - 1) ? s[row + 1] : 0.f;
  const float* P = PQ;
  const float* Q = PQ + 768;
  float acc = 0.f;
  float a, m;
  a = fmaxf(sm, 0.f); m = fmaxf(-sm, 0.f);
  acc += a * P[0*256+co] + m * Q[0*256+co];
  a = fmaxf(s0, 0.f); m = fmaxf(-s0, 0.f);
  acc += a * P[1*256+co] + m * Q[1*256+co];
  a = fmaxf(sp, 0.f); m = fmaxf(-sp, 0.f);
  acc += a * P[2*256+co] + m * Q[2*256+co];
  C2[(size_t)row * 256 + co] = f2h(fmaxf(acc, 0.f));
}

// ---------------- MFMA GEMM, K=256 fixed. B given TRANSPOSED [n][256].
// mode 0: direct rows; out = relu(acc) + relu(s*k1aw+k1ab)   (conv3+conv1a -> enc)
// mode 2: gathered rows (chain/time-chunk); out = acc + bcat[dir*800+col]
__global__ __launch_bounds__(256, 2) void gemm_kernel(
    const unsigned short* __restrict__ Ag, const unsigned short* __restrict__ Bg0,
    int N, int ntiles, int mode,
    unsigned short* __restrict__ Outp,
    const float* __restrict__ bias, const float* __restrict__ Sg,
    const float* __restrict__ k1aw, const float* __restrict__ k1ab,
    const int* __restrict__ lens, int t0)
{
  __shared__ __align__(16) unsigned short Bl[128*128]; // [n][k-phase], xor-swizzled 16B chunks
  __shared__ __align__(16) unsigned short Al[128*40];  // [m][k32], pad 40 halves
  __shared__ int rowsrc[128];
  int tid = threadIdx.x;
  int tm = blockIdx.x / ntiles, tn = blockIdx.x % ntiles;
  int col0 = tn * 128;
  int lane = tid & 63, wv = tid >> 6;
  int quad = lane >> 4, l16 = lane & 15;
  int wrow = (wv & 1) * 64, wcol = (wv >> 1) * 64;

  int dirv = 0;
  if (mode == 2) dirv = ((tm * 128) >> 8) >> 5;   // chain = m/TB ; dir = chain>>5
  const unsigned short* Bg = Bg0 + (size_t)dirv * 204800;

  if (tid < 128) {
    int r;
    if (mode == 2) {
      int m = tm * 128 + tid;
      int ch = m >> 8;              // TB=256
      int ls = m & 255;
      int b = ch & 31, dd = ch >> 5;
      int L = lens[b]; L = (L < 0) ? 0 : ((L > T_LEN) ? T_LEN : L);
      int t = t0 + ls;
      int src = dd ? (L - 1 - t) : t;
      src = (src < 0) ? 0 : ((src > T_LEN - 1) ? (T_LEN - 1) : src);
      r = b * T_LEN + src;
    } else {
      r = tm * 128 + tid;
    }
    rowsrc[tid] = r;
  }

  floatx4 acc[16];
  #pragma unroll
  for (int i = 0; i < 16; ++i) acc[i] = (floatx4){0.f,0.f,0.f,0.f};

  for (int ph = 0; ph < 2; ++ph) {
    __syncthreads();
    // stage B half-panel from BT: rows n in [col0,col0+128), k in [ph*128, +128)
    #pragma unroll
    for (int it = 0; it < 8; ++it) {
      int idx = it * 256 + tid;             // 2048 b128 chunks
      int n  = idx >> 4;                    // 0..127 local col
      int k8 = idx & 15;                    // 16B chunk within phase
      int nn = col0 + n;
      uint4 v = (uint4){0u,0u,0u,0u};
      if (nn < N) v = *(const uint4*)(Bg + (size_t)nn * 256 + ph * 128 + k8 * 8);
      *(uint4*)(&Bl[n * 128 + ((k8 ^ (n & 7)) * 8)]) = v;
    }
    for (int kb2 = 0; kb2 < 4; ++kb2) {
      int kb = ph * 4 + kb2;
      __syncthreads();
      #pragma unroll
      for (int i = 0; i < 2; ++i) {
        int c2 = i * 256 + tid;
        int r = c2 >> 2, kc = (c2 & 3) * 8;
        uint4 v = *(const uint4*)(Ag + (size_t)rowsrc[r] * 256 + kb * 32 + kc);
        *(uint4*)(&Al[r * 40 + kc]) = v;
      }
      __syncthreads();
      f16x8 af[4], bfr[4];
      #pragma unroll
      for (int mt = 0; mt < 4; ++mt)
        af[mt] = *(const f16x8*)(&Al[(wrow + mt*16 + l16) * 40 + quad * 8]);
      #pragma unroll
      for (int nt = 0; nt < 4; ++nt) {
        int nl = wcol + nt*16 + l16;
        int c = kb2 * 4 + quad;
        bfr[nt] = *(const f16x8*)(&Bl[nl * 128 + ((c ^ (nl & 7)) * 8)]);
      }
      #pragma unroll
      for (int mt = 0; mt < 4; ++mt)
        #pragma unroll
        for (int nt = 0; nt < 4; ++nt)
          acc[mt*4+nt] = __builtin_amdgcn_mfma_f32_16x16x32_f16(af[mt], bfr[nt], acc[mt*4+nt], 0, 0, 0);
    }
  }
  #pragma unroll
  for (int mt = 0; mt < 4; ++mt) {
    #pragma unroll
    for (int nt = 0; nt < 4; ++nt) {
      floatx4 v = acc[mt*4+nt];
      int col = col0 + wcol + nt*16 + l16;
      if (col < N) {
        #pragma unroll
        for (int r = 0; r < 4; ++r) {
          int row = tm * 128 + wrow + mt*16 + quad*4 + r;
          float x = v[r];
          float o;
          if (mode == 0) {
            float sv = Sg[row];
            float a1 = sv * k1aw[col] + k1ab[col];
            o = fmaxf(x, 0.f) + fmaxf(a1, 0.f);
          } else {
            o = x + bias[dirv * 800 + col];
          }
          Outp[(size_t)row * N + col] = f2h(o);
        }
      }
    }
  }
}

// ---------------- 5-way k-chunk dot2 recurrent LSTM: one WG per (sample, direction),
// 1024 thr (16 waves). Worker tid<1000: s = tid/200 (k-chunk [40s,40s+40)), n = tid%200.
// Each worker: partials of ALL FOUR gates of unit n over its 40-k chunk = 80 dot2,
// 5 broadcast b128 h-reads. s>0 write float4 partials to LDS; s=0 (tid<200) sums 4
// partials + own, does activation. 2 barriers/step (compiler __syncthreads — the
// R11 raw-barrier experiment regressed, reverted).
// REGISTER-PRESSURE FIX (R12 post-mortem): R9 materialized hd[20] across the whole
// 80-dot loop -> peak live ~125 at the 128-reg cliff -> allocator demoted w[] to
// AGPRs (VGPR_Count=64) and shuttled per dot. Here each h-uint4 is consumed
// immediately (16 dots per load, hv dies per iteration): peak live ~98 < 128 so
// w[] can stay in arch VGPRs. Identical math and accumulation order to R9.
__global__ __launch_bounds__(1024, 4)
void lstm_kernel(
    const unsigned short* __restrict__ XWbuf,  // [64][TB][800] f16, cols c=4n+q, bias(+1 f) folded
    const unsigned short* __restrict__ WhK,    // 5-way k-chunk weight records (see prep)
    const int* __restrict__ lens,
    unsigned short* __restrict__ fwH, unsigned short* __restrict__ bwH,
    float* __restrict__ cState, unsigned short* __restrict__ hState,
    int t0)
{
  int ch  = blockIdx.x;
  int dir = ch >> 5;
  int b   = ch & 31;
  int L = lens[b];
  L = (L < 0) ? 0 : ((L > T_LEN) ? T_LEN : L);
  int tend = t0 + TB; if (tend > L) tend = L;
  int tid = threadIdx.x;
  bool worker = tid < 1000;
  int s = tid / 200;                    // k-chunk (workers)
  int n = tid - s * 200;                // unit (workers)

  __shared__ __align__(16) unsigned short xw_lds[2][SB*800]; // 25.6 KB
  __shared__ __align__(16) unsigned short hist[SB*200];      // 3.2 KB
  __shared__ __align__(16) unsigned short himg[2][200];      // linear h, dbuf (800 B)
  __shared__ __align__(16) floatx4 zp[800];                  // 12.8 KB partial-z (s=1..4)

  // zero both h buffers
  if (tid < 200) ((unsigned int*)himg)[tid] = 0u;

  float c = 0.f;
  unsigned short last_h = 0;
  if (tid < 200 && t0 > 0) {
    c = cState[ch * HH + tid];
    last_h = hState[ch * HH + tid];
  }
  __syncthreads();
  if (tid < 200 && t0 > 0) himg[0][tid] = last_h;

  // persistent weights: 4 gates x 20 dwords = 80 dwords, compile-time indexed.
  unsigned int w[80];
  if (worker) {
    const uint4* wp = (const uint4*)(WhK + ((size_t)((dir * 5 + s) * 200 + n)) * 160);
    #pragma unroll
    for (int r = 0; r < 20; ++r) {
      uint4 v = wp[r];
      w[4*r+0] = v.x; w[4*r+1] = v.y; w[4*r+2] = v.z; w[4*r+3] = v.w;
    }
    #pragma unroll
    for (int r = 0; r < 80; ++r)
      asm volatile("" : "+v"(w[r]));
  }

  unsigned short* Hd = dir ? bwH : fwH;
  const unsigned short* XWc = XWbuf + ((size_t)ch * TB) * 800;

  // DMA block 0 into xw_lds[0] (1024 threads cover 800 chunks in one shot)
  if (t0 < tend && tid < 800)
    GLD_LDS16(XWc + (size_t)tid * 8, &xw_lds[0][tid * 8]);
  __syncthreads();   // drains DMA; h state visible

  int buf = 0, cur = 0;
  int prev_tb = -1, prev_cnt = 0;

  for (int tb = t0; tb < tend; tb += SB) {
    int cnt = tend - tb; if (cnt > SB) cnt = SB;
    for (int sl = 0; sl < cnt; ++sl) {
      if (sl == 0) {
        // DMA next block into the other buffer (drains at a later barrier)
        int ntb = tb + SB;
        if ((ntb - t0) < TB && tid < 800) {
          const unsigned short* src = XWc + (size_t)(ntb - t0) * 800;
          GLD_LDS16(src + (size_t)tid * 8, &xw_lds[buf ^ 1][tid * 8]);
        }
        // flush previous block's h history
        if (prev_tb >= 0) {
          int pcnt = prev_cnt;
          if (tid < pcnt * 25) {
            int srow = dir ? (pcnt - 1 - tid / 25) : (tid / 25);
            uint4 v = *(const uint4*)&hist[srow*200 + (tid % 25)*8];
            size_t base = dir ? ((size_t)(b*T_LEN + (L - prev_tb - pcnt)))*HH
                              : ((size_t)(b*T_LEN + prev_tb))*HH;
            *(uint4*)(Hd + base + (size_t)tid*8) = v;
          }
        }
      }
      float a0 = 0.f, a1 = 0.f, a2 = 0.f, a3 = 0.f;
      if (worker) {
        // 5 broadcast b128 reads of this chunk's h slice, each consumed
        // immediately (16 dots per load) — hv dies per iteration, keeping
        // peak register pressure below the 128-reg cliff.
        const uint4* hp = (const uint4*)(&himg[cur][s * 40]);
        #pragma unroll
        for (int r = 0; r < 5; ++r) {
          uint4 hv = hp[r];
          int d = r * 4;
          a0 = dot2f(hv.x, w[d],      a0); a1 = dot2f(hv.x, w[20 + d], a1);
          a2 = dot2f(hv.x, w[40 + d], a2); a3 = dot2f(hv.x, w[60 + d], a3);
          a0 = dot2f(hv.y, w[d + 1],  a0); a1 = dot2f(hv.y, w[21 + d], a1);
          a2 = dot2f(hv.y, w[41 + d], a2); a3 = dot2f(hv.y, w[61 + d], a3);
          a0 = dot2f(hv.z, w[d + 2],  a0); a1 = dot2f(hv.z, w[22 + d], a1);
          a2 = dot2f(hv.z, w[42 + d], a2); a3 = dot2f(hv.z, w[62 + d], a3);
          a0 = dot2f(hv.w, w[d + 3],  a0); a1 = dot2f(hv.w, w[23 + d], a1);
          a2 = dot2f(hv.w, w[43 + d], a2); a3 = dot2f(hv.w, w[63 + d], a3);
        }
        if (s != 0) {
          floatx4 z; z[0] = a0; z[1] = a1; z[2] = a2; z[3] = a3;
          zp[(s - 1) * 200 + n] = z;
        }
      }
      __syncthreads();   // partials visible; himg[cur] reads complete
      if (tid < 200) {   // s==0 worker, n == tid
        floatx4 p0 = zp[tid], p1 = zp[200 + tid], p2 = zp[400 + tid], p3 = zp[600 + tid];
        uint2 xv = *(const uint2*)&xw_lds[buf][sl*800 + 4*tid];
        f16x2 xa = __builtin_bit_cast(f16x2, xv.x);
        f16x2 xb = __builtin_bit_cast(f16x2, xv.y);
        float zi = a0 + p0[0] + p1[0] + p2[0] + p3[0] + (float)xa[0];
        float zj = a1 + p0[1] + p1[1] + p2[1] + p3[1] + (float)xa[1];
        float zf = a2 + p0[2] + p1[2] + p2[2] + p3[2] + (float)xb[0];
        float zo = a3 + p0[3] + p1[3] + p2[3] + p3[3] + (float)xb[1];
        c = c * sigm(zf) + sigm(zi) * tanh_fast(zj);
        float h = tanh_fast(c) * sigm(zo);
        unsigned short hh = f2h(h);
        last_h = hh;
        himg[cur ^ 1][tid] = hh;
        hist[sl*200 + tid] = hh;
      }
      cur ^= 1;
      __syncthreads();   // new h visible for next step
    }
    prev_tb = tb; prev_cnt = cnt; buf ^= 1;
  }
  // final flush + state save
  if (prev_tb >= 0) {
    int pcnt = prev_cnt;
    if (tid < pcnt * 25) {
      int srow = dir ? (pcnt - 1 - tid / 25) : (tid / 25);
      uint4 v = *(const uint4*)&hist[srow*200 + (tid % 25)*8];
      size_t base = dir ? ((size_t)(b*T_LEN + (L - prev_tb - pcnt)))*HH
                        : ((size_t)(b*T_LEN + prev_tb))*HH;
      *(uint4*)(Hd + base + (size_t)tid*8) = v;
    }
  }
  if (tid < 200) {
    cState[ch * HH + tid] = c;
    hState[ch * HH + tid] = last_h;
  }
}

// ---------------- logits = [fwH|bwH] @ Wd + bd
__global__ __launch_bounds__(256) void out_kernel(
    const unsigned short* __restrict__ fwH, const unsigned short* __restrict__ bwH,
    const float* __restrict__ Wd, const float* __restrict__ bd, float* __restrict__ out)
{
  __shared__ float wd[2000];
  int tid = threadIdx.x;
  for (int i = tid; i < 2000; i += 256) wd[i] = Wd[i];
  __syncthreads();
  int row = blockIdx.x * 256 + tid;
  float acc0 = bd[0], acc1 = bd[1], acc2 = bd[2], acc3 = bd[3], acc4 = bd[4];
  const unsigned int* fu = (const unsigned int*)(fwH + (size_t)row * HH);
  const unsigned int* bu = (const unsigned int*)(bwH + (size_t)row * HH);
  #pragma unroll 4
  for (int i = 0; i < 100; ++i) {
    f16x2 pf = __builtin_bit_cast(f16x2, fu[i]);
    f16x2 pb = __builtin_bit_cast(f16x2, bu[i]);
    int k = 2 * i;
    float f0 = (float)pf[0], f1 = (float)pf[1];
    float b0 = (float)pb[0], b1 = (float)pb[1];
    const float* w0 = &wd[k*5];
    const float* w1 = &wd[(k+1)*5];
    const float* w2 = &wd[(200+k)*5];
    const float* w3 = &wd[(201+k)*5];
    acc0 += f0*w0[0] + f1*w1[0] + b0*w2[0] + b1*w3[0];
    acc1 += f0*w0[1] + f1*w1[1] + b0*w2[1] + b1*w3[1];
    acc2 += f0*w0[2] + f1*w1[2] + b0*w2[2] + b1*w3[2];
    acc3 += f0*w0[3] + f1*w1[3] + b0*w2[3] + b1*w3[3];
    acc4 += f0*w0[4] + f1*w1[4] + b0*w2[4] + b1*w3[4];
  }
  float* o = out + (size_t)row * 5;
  o[0]=acc0; o[1]=acc1; o[2]=acc2; o[3]=acc3; o[4]=acc4;
}

extern "C" void kernel_launch(void* const* d_in, const int* in_sizes, int n_in,
                              void* d_out, int out_size, void* d_ws, size_t ws_size,
                              hipStream_t stream)
{
  const float* signals = (const float*)d_in[0];
  const int*   lens    = (const int*)  d_in[1];
  const float* k1w     = (const float*)d_in[2];
  const float* k1aw    = (const float*)d_in[3];
  const float* k1ab    = (const float*)d_in[4];
  const float* k2w     = (const float*)d_in[5];
  const float* k3w     = (const float*)d_in[6];
  const float* Wf      = (const float*)d_in[7];
  const float* bf      = (const float*)d_in[8];
  const float* Wb      = (const float*)d_in[9];
  const float* bb      = (const float*)d_in[10];
  const float* Wd      = (const float*)d_in[11];
  const float* bd      = (const float*)d_in[12];
  float* out = (float*)d_out;
  char* ws = (char*)d_ws;

  // Region A aliases C2 (conv phase) and XWbuf (LSTM phase) — disjoint lifetimes.
  size_t szC2   = (size_t)NROWS * 256 * 2;          // 33,554,432
  size_t szXWb  = (size_t)64 * TB * 800 * 2;        // 26,214,400
  size_t szA    = (szC2 > szXWb) ? szC2 : szXWb;
  size_t oA   = 0;
  size_t oE   = oA   + szA;
  size_t oFw  = oE   + (size_t)NROWS*256*2;
  size_t oBw  = oFw  + (size_t)NROWS*HH*2;
  size_t oWhK = oBw  + (size_t)NROWS*HH*2;
  size_t oWx2 = oWhK + (size_t)320000*2;            // 640,000
  size_t oK3  = oWx2 + (size_t)2*256*800*2;
  size_t oPQ  = oK3  + (size_t)256*256*2;
  size_t oBc  = oPQ  + 1536*4;
  size_t oCst = oBc  + 1600*4;
  size_t oHst = oCst + (size_t)64*HH*4;
  size_t total= oHst + (size_t)64*HH*2;
  if (ws_size < total) return;

  unsigned short* C2    = (unsigned short*)(ws + oA);
  unsigned short* XWbuf = (unsigned short*)(ws + oA);
  unsigned short* E     = (unsigned short*)(ws + oE);
  unsigned short* fwH   = (unsigned short*)(ws + oFw);
  unsigned short* bwH   = (unsigned short*)(ws + oBw);
  unsigned short* WhK   = (unsigned short*)(ws + oWhK);
  unsigned short* Wx2   = (unsigned short*)(ws + oWx2);
  unsigned short* K3h   = (unsigned short*)(ws + oK3);
  float* PQ     = (float*)(ws + oPQ);
  float* bcat   = (float*)(ws + oBc);
  float* cState = (float*)(ws + oCst);
  unsigned short* hState = (unsigned short*)(ws + oHst);

  (void)hipMemsetAsync(fwH, 0, (size_t)2*NROWS*HH*2, stream);
  pq_kernel  <<<6,     256, 0, stream>>>(k1w, k2w, PQ);
  prep_kernel<<<3113,  256, 0, stream>>>(k3w, Wf, bf, Wb, bb, K3h, Wx2, WhK, bcat);
  conv2_kernel<<<NROWS, 256, 0, stream>>>(signals, PQ, C2);
  gemm_kernel<<<1024,  256, 0, stream>>>(C2, K3h, 256, 2, 0, E, nullptr, signals, k1aw, k1ab, nullptr, 0);
  for (int t0 = 0; t0 < T_LEN; t0 += TB) {
    gemm_kernel<<<896, 256, 0, stream>>>(E, Wx2, 800, 7, 2, XWbuf, bcat, nullptr, nullptr, nullptr, lens, t0);
    lstm_kernel<<<64, 1024, 0, stream>>>(XWbuf, WhK, lens, fwH, bwH, cState, hState, t0);
  }
  out_kernel <<<256,   256, 0, stream>>>(fwH, bwH, Wd, bd, out);
}

// Round 15
// 2347.151 us; speedup vs baseline: 5.3534x; 1.0964x over previous
//
#include <hip/hip_runtime.h>
#include <cstdint>

#define T_LEN 2048
#define NB    32
#define NROWS (NB*T_LEN)   // 65536
#define HH    200
#define G4    800
#define TB    128          // LSTM time-chunk (per mega launch)
#define SB    8            // step block staged in LDS
#define XWSZ  ((size_t)64 * TB * 800)   // halves per XW buffer

typedef _Float16 f16;
typedef _Float16 f16x2 __attribute__((ext_vector_type(2)));
typedef _Float16 f16x8 __attribute__((ext_vector_type(8)));
typedef float   floatx4 __attribute__((ext_vector_type(4)));

#define GLD_LDS16(g, l) __builtin_amdgcn_global_load_lds( \
    (const __attribute__((address_space(1))) void*)(g), \
    (__attribute__((address_space(3))) void*)(l), 16, 0, 0)

static __device__ __forceinline__ unsigned short f2h(float x) {
  f16 h = (f16)x; return __builtin_bit_cast(unsigned short, h);
}
static __device__ __forceinline__ float dot2f(unsigned int a, unsigned int b, float c) {
  return __builtin_amdgcn_fdot2(__builtin_bit_cast(f16x2, a),
                                __builtin_bit_cast(f16x2, b), c, false);
}
static __device__ __forceinline__ float sigm(float x) {
  return __builtin_amdgcn_rcpf(1.f + __expf(-x));
}
static __device__ __forceinline__ float tanh_fast(float x) {
  return 1.f - 2.f * __builtin_amdgcn_rcpf(__expf(2.f * x) + 1.f);
}

// ---------------- P/Q precompute: P[dt,co]=sum_ci relu(k1)k2, Q with relu(-k1)
__global__ void pq_kernel(const float* __restrict__ k1w, const float* __restrict__ k2w,
                          float* __restrict__ PQ) {
  int id = blockIdx.x * 256 + threadIdx.x;   // 1536 total
  int pq = id / 768;
  int rem = id % 768;
  int wdt = rem / 256;
  int co  = rem % 256;
  float acc = 0.f;
  for (int ci = 0; ci < 256; ++ci) {
    float k = k1w[ci];
    float kk = pq ? fmaxf(-k, 0.f) : fmaxf(k, 0.f);
    acc += kk * k2w[((size_t)wdt * 256 + ci) * 256 + co];
  }
  PQ[id] = acc;
}

// ---------------- f16 weight prep (B matrices stored TRANSPOSED: [n][k])
// K3T[co][ci] ; Wx2[dir][c][k] with permuted col c=4n+q (gate g=q*200+n) ;
// WhK: per-thread 5-way k-chunk weight records [dir][s<5][n<200][4 gates][40 halves] ;
// bcat permuted, f-gate +1 folded.
__global__ void prep_kernel(const float* __restrict__ k3w,
                            const float* __restrict__ Wf, const float* __restrict__ bfv,
                            const float* __restrict__ Wb, const float* __restrict__ bbv,
                            unsigned short* __restrict__ K3h, unsigned short* __restrict__ Wx2,
                            unsigned short* __restrict__ WhK, float* __restrict__ bcat) {
  int id = blockIdx.x * 256 + threadIdx.x;
  if (id < 65536) {                      // K3T[co*256+ci] = k3w[ci*256+co]
    K3h[id] = f2h(k3w[(id & 255) * 256 + (id >> 8)]);
    return;
  }
  id -= 65536;
  if (id < 409600) {                     // Wx2[dir][c<800][k<256]
    int dirv = id / 204800;
    int r = id % 204800;
    int c = r >> 8, k = r & 255;
    int n = c >> 2, q = c & 3;
    int g = q * 200 + n;
    const float* W = dirv ? Wb : Wf;
    Wx2[id] = f2h(W[k * 800 + g]);
    return;
  }
  id -= 409600;
  if (id < 320000) {                     // WhK halves: 2*5*200*160
    int rec = id / 160;
    int m   = id % 160;
    int g   = m / 40, j = m % 40;
    int n   = rec % 200;
    int t2  = rec / 200;                 // 0..9
    int s   = t2 % 5, dirv = t2 / 5;
    int k   = s * 40 + j;
    const float* W = dirv ? Wb : Wf;
    WhK[id] = f2h(W[(256 + k) * 800 + (g * 200 + n)]);
    return;
  }
  id -= 320000;
  if (id < 1600) {                       // bcat[dir*800 + c] with same perm; +1 on f gate
    int dirv = id / 800;
    int c = id % 800;
    int n = c >> 2, q = c & 3;
    int g = q * 200 + n;
    bcat[id] = (dirv ? bbv : bfv)[g] + (q == 2 ? 1.f : 0.f);
  }
}

// ---------------- conv2 via rank-1 collapse (6 FMA/elem)
__global__ void conv2_kernel(const float* __restrict__ s, const float* __restrict__ PQ,
                             unsigned short* __restrict__ C2) {
  int row = blockIdx.x;
  int co  = threadIdx.x;
  int t = row & (T_LEN - 1);
  float s0 = s[row];
  float sm = (t > 0)         ? s[row - 1] : 0.f;
  float sp = (t < T_LEN - 1) ? s[row + 1] : 0.f;
  const float* P = PQ;
  const float* Q = PQ + 768;
  float acc = 0.f;
  float a, m;
  a = fmaxf(sm, 0.f); m = fmaxf(-sm, 0.f);
  acc += a * P[0*256+co] + m * Q[0*256+co];
  a = fmaxf(s0, 0.f); m = fmaxf(-s0, 0.f);
  acc += a * P[1*256+co] + m * Q[1*256+co];
  a = fmaxf(sp, 0.f); m = fmaxf(-sp, 0.f);
  acc += a * P[2*256+co] + m * Q[2*256+co];
  C2[(size_t)row * 256 + co] = f2h(fmaxf(acc, 0.f));
}

// ---------------- MFMA GEMM, K=256 fixed. B given TRANSPOSED [n][256].
// mode 0: direct rows; out = relu(acc) + relu(s*k1aw+k1ab)   (conv3+conv1a -> enc)
// mode 2: gathered rows (chain/time-chunk, TB=128); out = acc + bcat[dir*800+col]
__global__ __launch_bounds__(256, 2) void gemm_kernel(
    const unsigned short* __restrict__ Ag, const unsigned short* __restrict__ Bg0,
    int N, int ntiles, int mode,
    unsigned short* __restrict__ Outp,
    const float* __restrict__ bias, const float* __restrict__ Sg,
    const float* __restrict__ k1aw, const float* __restrict__ k1ab,
    const int* __restrict__ lens, int t0)
{
  __shared__ __align__(16) unsigned short Bl[128*128]; // [n][k-phase], xor-swizzled 16B chunks
  __shared__ __align__(16) unsigned short Al[128*40];  // [m][k32], pad 40 halves
  __shared__ int rowsrc[128];
  int tid = threadIdx.x;
  int tm = blockIdx.x / ntiles, tn = blockIdx.x % ntiles;
  int col0 = tn * 128;
  int lane = tid & 63, wv = tid >> 6;
  int quad = lane >> 4, l16 = lane & 15;
  int wrow = (wv & 1) * 64, wcol = (wv >> 1) * 64;

  int dirv = 0;
  if (mode == 2) dirv = tm >> 5;   // TB=128: row-tile == chain ; dir = chain>>5
  const unsigned short* Bg = Bg0 + (size_t)dirv * 204800;

  if (tid < 128) {
    int r;
    if (mode == 2) {
      int m = tm * 128 + tid;
      int ch = m >> 7;              // TB=128
      int ls = m & 127;
      int b = ch & 31, dd = ch >> 5;
      int L = lens[b]; L = (L < 0) ? 0 : ((L > T_LEN) ? T_LEN : L);
      int t = t0 + ls;
      int src = dd ? (L - 1 - t) : t;
      src = (src < 0) ? 0 : ((src > T_LEN - 1) ? (T_LEN - 1) : src);
      r = b * T_LEN + src;
    } else {
      r = tm * 128 + tid;
    }
    rowsrc[tid] = r;
  }

  floatx4 acc[16];
  #pragma unroll
  for (int i = 0; i < 16; ++i) acc[i] = (floatx4){0.f,0.f,0.f,0.f};

  for (int ph = 0; ph < 2; ++ph) {
    __syncthreads();
    // stage B half-panel from BT: rows n in [col0,col0+128), k in [ph*128, +128)
    #pragma unroll
    for (int it = 0; it < 8; ++it) {
      int idx = it * 256 + tid;             // 2048 b128 chunks
      int n  = idx >> 4;                    // 0..127 local col
      int k8 = idx & 15;                    // 16B chunk within phase
      int nn = col0 + n;
      uint4 v = (uint4){0u,0u,0u,0u};
      if (nn < N) v = *(const uint4*)(Bg + (size_t)nn * 256 + ph * 128 + k8 * 8);
      *(uint4*)(&Bl[n * 128 + ((k8 ^ (n & 7)) * 8)]) = v;
    }
    for (int kb2 = 0; kb2 < 4; ++kb2) {
      int kb = ph * 4 + kb2;
      __syncthreads();
      #pragma unroll
      for (int i = 0; i < 2; ++i) {
        int c2 = i * 256 + tid;
        int r = c2 >> 2, kc = (c2 & 3) * 8;
        uint4 v = *(const uint4*)(Ag + (size_t)rowsrc[r] * 256 + kb * 32 + kc);
        *(uint4*)(&Al[r * 40 + kc]) = v;
      }
      __syncthreads();
      f16x8 af[4], bfr[4];
      #pragma unroll
      for (int mt = 0; mt < 4; ++mt)
        af[mt] = *(const f16x8*)(&Al[(wrow + mt*16 + l16) * 40 + quad * 8]);
      #pragma unroll
      for (int nt = 0; nt < 4; ++nt) {
        int nl = wcol + nt*16 + l16;
        int c = kb2 * 4 + quad;
        bfr[nt] = *(const f16x8*)(&Bl[nl * 128 + ((c ^ (nl & 7)) * 8)]);
      }
      #pragma unroll
      for (int mt = 0; mt < 4; ++mt)
        #pragma unroll
        for (int nt = 0; nt < 4; ++nt)
          acc[mt*4+nt] = __builtin_amdgcn_mfma_f32_16x16x32_f16(af[mt], bfr[nt], acc[mt*4+nt], 0, 0, 0);
    }
  }
  #pragma unroll
  for (int mt = 0; mt < 4; ++mt) {
    #pragma unroll
    for (int nt = 0; nt < 4; ++nt) {
      floatx4 v = acc[mt*4+nt];
      int col = col0 + wcol + nt*16 + l16;
      if (col < N) {
        #pragma unroll
        for (int r = 0; r < 4; ++r) {
          int row = tm * 128 + wrow + mt*16 + quad*4 + r;
          float x = v[r];
          float o;
          if (mode == 0) {
            float sv = Sg[row];
            float a1 = sv * k1aw[col] + k1ab[col];
            o = fmaxf(x, 0.f) + fmaxf(a1, 0.f);
          } else {
            o = x + bias[dirv * 800 + col];
          }
          Outp[(size_t)row * N + col] = f2h(o);
        }
      }
    }
  }
}

// ---------------- MEGA kernel: lstm(chunk k) || gemm(chunk k+1), one launch.
// Grid 214 x 1024 thr. Blocks 0-63: the R13-verified 5-way k-chunk dot2 LSTM for
// chain blockIdx, chunk k (reads XW buffer k&1). Blocks 64-213: mode-2 XW GEMM for
// chunk k+1 (writes buffer (k+1)&1), 3 tile-tasks each (448 tasks), work guarded
// by tid<256 with barriers at block-uniform points. Both LDS structs declared ->
// ~85KB -> exactly 1 block/CU, so no CU ever hosts two lstm blocks. The GEMM time
// (and its old per-dispatch launch overhead) hides entirely under the 64-CU lstm.
// R14 fix: restored the N=800 boundary guards (B-stage nn<800 zero-fill, output
// col<800 skip) that the fusion inlining dropped — cols 768..895 of the last
// column-tile were wrapping into the next row (absmax 0.347).
__global__ __launch_bounds__(1024, 4)
void mega_kernel(
    const unsigned short* __restrict__ Eg,     // enc rows [NROWS][256]
    const unsigned short* __restrict__ Wx2,    // gemm B (transposed, per dir)
    unsigned short* __restrict__ XWbuf,        // double buffer base
    const float* __restrict__ bcat,
    const unsigned short* __restrict__ WhK,    // lstm weight records
    const int* __restrict__ lens,
    unsigned short* __restrict__ fwH, unsigned short* __restrict__ bwH,
    float* __restrict__ cState, unsigned short* __restrict__ hState,
    int k)                                     // chunk index
{
  __shared__ __align__(16) unsigned short xw_lds[2][SB*800]; // 25.6 KB (lstm)
  __shared__ __align__(16) unsigned short hist[SB*200];      // 3.2 KB  (lstm)
  __shared__ __align__(16) unsigned short himg[2][200];      // 0.8 KB  (lstm)
  __shared__ __align__(16) floatx4 zp[800];                  // 12.8 KB (lstm)
  __shared__ __align__(16) unsigned short Bl[128*128];       // 32 KB   (gemm)
  __shared__ __align__(16) unsigned short Al[128*40];        // 10 KB   (gemm)
  __shared__ int rowsrc[128];                                //          (gemm)

  int tid = threadIdx.x;
  int t0 = k * TB;

  if (blockIdx.x < 64) {
    // ================= LSTM part (R13 body, TB=128) =================
    int ch  = blockIdx.x;
    int dir = ch >> 5;
    int b   = ch & 31;
    int L = lens[b];
    L = (L < 0) ? 0 : ((L > T_LEN) ? T_LEN : L);
    int tend = t0 + TB; if (tend > L) tend = L;
    bool worker = tid < 1000;
    int s = tid / 200;
    int n = tid - s * 200;

    if (tid < 200) ((unsigned int*)himg)[tid] = 0u;

    float c = 0.f;
    unsigned short last_h = 0;
    if (tid < 200 && t0 > 0) {
      c = cState[ch * HH + tid];
      last_h = hState[ch * HH + tid];
    }
    __syncthreads();
    if (tid < 200 && t0 > 0) himg[0][tid] = last_h;

    unsigned int w[80];
    if (worker) {
      const uint4* wp = (const uint4*)(WhK + ((size_t)((dir * 5 + s) * 200 + n)) * 160);
      #pragma unroll
      for (int r = 0; r < 20; ++r) {
        uint4 v = wp[r];
        w[4*r+0] = v.x; w[4*r+1] = v.y; w[4*r+2] = v.z; w[4*r+3] = v.w;
      }
      #pragma unroll
      for (int r = 0; r < 80; ++r)
        asm volatile("" : "+v"(w[r]));
    }

    unsigned short* Hd = dir ? bwH : fwH;
    const unsigned short* XWc = XWbuf + (size_t)(k & 1) * XWSZ + ((size_t)ch * TB) * 800;

    if (t0 < tend && tid < 800)
      GLD_LDS16(XWc + (size_t)tid * 8, &xw_lds[0][tid * 8]);
    __syncthreads();

    int buf = 0, cur = 0;
    int prev_tb = -1, prev_cnt = 0;

    for (int tb = t0; tb < tend; tb += SB) {
      int cnt = tend - tb; if (cnt > SB) cnt = SB;
      for (int sl = 0; sl < cnt; ++sl) {
        if (sl == 0) {
          int ntb = tb + SB;
          if ((ntb - t0) < TB && tid < 800) {
            const unsigned short* src = XWc + (size_t)(ntb - t0) * 800;
            GLD_LDS16(src + (size_t)tid * 8, &xw_lds[buf ^ 1][tid * 8]);
          }
          if (prev_tb >= 0) {
            int pcnt = prev_cnt;
            if (tid < pcnt * 25) {
              int srow = dir ? (pcnt - 1 - tid / 25) : (tid / 25);
              uint4 v = *(const uint4*)&hist[srow*200 + (tid % 25)*8];
              size_t base = dir ? ((size_t)(b*T_LEN + (L - prev_tb - pcnt)))*HH
                                : ((size_t)(b*T_LEN + prev_tb))*HH;
              *(uint4*)(Hd + base + (size_t)tid*8) = v;
            }
          }
        }
        float a0 = 0.f, a1 = 0.f, a2 = 0.f, a3 = 0.f;
        if (worker) {
          const uint4* hp = (const uint4*)(&himg[cur][s * 40]);
          #pragma unroll
          for (int r = 0; r < 5; ++r) {
            uint4 hv = hp[r];
            int d = r * 4;
            a0 = dot2f(hv.x, w[d],      a0); a1 = dot2f(hv.x, w[20 + d], a1);
            a2 = dot2f(hv.x, w[40 + d], a2); a3 = dot2f(hv.x, w[60 + d], a3);
            a0 = dot2f(hv.y, w[d + 1],  a0); a1 = dot2f(hv.y, w[21 + d], a1);
            a2 = dot2f(hv.y, w[41 + d], a2); a3 = dot2f(hv.y, w[61 + d], a3);
            a0 = dot2f(hv.z, w[d + 2],  a0); a1 = dot2f(hv.z, w[22 + d], a1);
            a2 = dot2f(hv.z, w[42 + d], a2); a3 = dot2f(hv.z, w[62 + d], a3);
            a0 = dot2f(hv.w, w[d + 3],  a0); a1 = dot2f(hv.w, w[23 + d], a1);
            a2 = dot2f(hv.w, w[43 + d], a2); a3 = dot2f(hv.w, w[63 + d], a3);
          }
          if (s != 0) {
            floatx4 z; z[0] = a0; z[1] = a1; z[2] = a2; z[3] = a3;
            zp[(s - 1) * 200 + n] = z;
          }
        }
        __syncthreads();
        if (tid < 200) {
          floatx4 p0 = zp[tid], p1 = zp[200 + tid], p2 = zp[400 + tid], p3 = zp[600 + tid];
          uint2 xv = *(const uint2*)&xw_lds[buf][sl*800 + 4*tid];
          f16x2 xa = __builtin_bit_cast(f16x2, xv.x);
          f16x2 xb = __builtin_bit_cast(f16x2, xv.y);
          float zi = a0 + p0[0] + p1[0] + p2[0] + p3[0] + (float)xa[0];
          float zj = a1 + p0[1] + p1[1] + p2[1] + p3[1] + (float)xa[1];
          float zf = a2 + p0[2] + p1[2] + p2[2] + p3[2] + (float)xb[0];
          float zo = a3 + p0[3] + p1[3] + p2[3] + p3[3] + (float)xb[1];
          c = c * sigm(zf) + sigm(zi) * tanh_fast(zj);
          float h = tanh_fast(c) * sigm(zo);
          unsigned short hh = f2h(h);
          last_h = hh;
          himg[cur ^ 1][tid] = hh;
          hist[sl*200 + tid] = hh;
        }
        cur ^= 1;
        __syncthreads();
      }
      prev_tb = tb; prev_cnt = cnt; buf ^= 1;
    }
    if (prev_tb >= 0) {
      int pcnt = prev_cnt;
      if (tid < pcnt * 25) {
        int srow = dir ? (pcnt - 1 - tid / 25) : (tid / 25);
        uint4 v = *(const uint4*)&hist[srow*200 + (tid % 25)*8];
        size_t base = dir ? ((size_t)(b*T_LEN + (L - prev_tb - pcnt)))*HH
                          : ((size_t)(b*T_LEN + prev_tb))*HH;
        *(uint4*)(Hd + base + (size_t)tid*8) = v;
      }
    }
    if (tid < 200) {
      cState[ch * HH + tid] = c;
      hState[ch * HH + tid] = last_h;
    }
    return;
  }

  // ================= GEMM part: chunk k+1 -> buffer (k+1)&1 =================
  int tgem = t0 + TB;
  if (tgem >= T_LEN) return;
  unsigned short* Outp = XWbuf + (size_t)((k + 1) & 1) * XWSZ;
  int lane = tid & 63, wv = tid >> 6;
  int quad = lane >> 4, l16 = lane & 15;
  int wrow = (wv & 1) * 64, wcol = (wv >> 1) * 64;

  for (int task = blockIdx.x - 64; task < 448; task += 150) {
    int tm = task / 7, tn = task % 7;
    int col0 = tn * 128;
    int dirv = tm >> 5;                  // chain == tm at TB=128
    const unsigned short* Bg = Wx2 + (size_t)dirv * 204800;

    __syncthreads();   // orders prior task's LDS reads before rewrite
    if (tid < 128) {
      int m = tm * 128 + tid;
      int chn = m >> 7;
      int ls = m & 127;
      int bb = chn & 31, dd = chn >> 5;
      int L = lens[bb]; L = (L < 0) ? 0 : ((L > T_LEN) ? T_LEN : L);
      int t = tgem + ls;
      int src = dd ? (L - 1 - t) : t;
      src = (src < 0) ? 0 : ((src > T_LEN - 1) ? (T_LEN - 1) : src);
      rowsrc[tid] = bb * T_LEN + src;
    }

    floatx4 acc[16];
    #pragma unroll
    for (int i = 0; i < 16; ++i) acc[i] = (floatx4){0.f,0.f,0.f,0.f};

    for (int ph = 0; ph < 2; ++ph) {
      __syncthreads();
      if (tid < 256) {
        #pragma unroll
        for (int it = 0; it < 8; ++it) {
          int idx = it * 256 + tid;
          int nl = idx >> 4;
          int k8 = idx & 15;
          int nn = col0 + nl;
          uint4 v = (uint4){0u,0u,0u,0u};
          if (nn < 800) v = *(const uint4*)(Bg + (size_t)nn * 256 + ph * 128 + k8 * 8);
          *(uint4*)(&Bl[nl * 128 + ((k8 ^ (nl & 7)) * 8)]) = v;
        }
      }
      for (int kb2 = 0; kb2 < 4; ++kb2) {
        int kb = ph * 4 + kb2;
        __syncthreads();
        if (tid < 256) {
          #pragma unroll
          for (int i = 0; i < 2; ++i) {
            int c2 = i * 256 + tid;
            int r = c2 >> 2, kc = (c2 & 3) * 8;
            uint4 v = *(const uint4*)(Eg + (size_t)rowsrc[r] * 256 + kb * 32 + kc);
            *(uint4*)(&Al[r * 40 + kc]) = v;
          }
        }
        __syncthreads();
        if (tid < 256) {
          f16x8 af[4], bfr[4];
          #pragma unroll
          for (int mt = 0; mt < 4; ++mt)
            af[mt] = *(const f16x8*)(&Al[(wrow + mt*16 + l16) * 40 + quad * 8]);
          #pragma unroll
          for (int nt = 0; nt < 4; ++nt) {
            int nl = wcol + nt*16 + l16;
            int cx = kb2 * 4 + quad;
            bfr[nt] = *(const f16x8*)(&Bl[nl * 128 + ((cx ^ (nl & 7)) * 8)]);
          }
          #pragma unroll
          for (int mt = 0; mt < 4; ++mt)
            #pragma unroll
            for (int nt = 0; nt < 4; ++nt)
              acc[mt*4+nt] = __builtin_amdgcn_mfma_f32_16x16x32_f16(af[mt], bfr[nt], acc[mt*4+nt], 0, 0, 0);
        }
      }
    }
    if (tid < 256) {
      #pragma unroll
      for (int mt = 0; mt < 4; ++mt) {
        #pragma unroll
        for (int nt = 0; nt < 4; ++nt) {
          floatx4 v = acc[mt*4+nt];
          int col = col0 + wcol + nt*16 + l16;
          if (col < 800) {
            #pragma unroll
            for (int r = 0; r < 4; ++r) {
              int row = tm * 128 + wrow + mt*16 + quad*4 + r;
              Outp[(size_t)row * 800 + col] = f2h(v[r] + bcat[dirv * 800 + col]);
            }
          }
        }
      }
    }
  }
}

// ---------------- logits = [fwH|bwH] @ Wd + bd
__global__ __launch_bounds__(256) void out_kernel(
    const unsigned short* __restrict__ fwH, const unsigned short* __restrict__ bwH,
    const float* __restrict__ Wd, const float* __restrict__ bd, float* __restrict__ out)
{
  __shared__ float wd[2000];
  int tid = threadIdx.x;
  for (int i = tid; i < 2000; i += 256) wd[i] = Wd[i];
  __syncthreads();
  int row = blockIdx.x * 256 + tid;
  float acc0 = bd[0], acc1 = bd[1], acc2 = bd[2], acc3 = bd[3], acc4 = bd[4];
  const unsigned int* fu = (const unsigned int*)(fwH + (size_t)row * HH);
  const unsigned int* bu = (const unsigned int*)(bwH + (size_t)row * HH);
  #pragma unroll 4
  for (int i = 0; i < 100; ++i) {
    f16x2 pf = __builtin_bit_cast(f16x2, fu[i]);
    f16x2 pb = __builtin_bit_cast(f16x2, bu[i]);
    int k = 2 * i;
    float f0 = (float)pf[0], f1 = (float)pf[1];
    float b0 = (float)pb[0], b1 = (float)pb[1];
    const float* w0 = &wd[k*5];
    const float* w1 = &wd[(k+1)*5];
    const float* w2 = &wd[(200+k)*5];
    const float* w3 = &wd[(201+k)*5];
    acc0 += f0*w0[0] + f1*w1[0] + b0*w2[0] + b1*w3[0];
    acc1 += f0*w0[1] + f1*w1[1] + b0*w2[1] + b1*w3[1];
    acc2 += f0*w0[2] + f1*w1[2] + b0*w2[2] + b1*w3[2];
    acc3 += f0*w0[3] + f1*w1[3] + b0*w2[3] + b1*w3[3];
    acc4 += f0*w0[4] + f1*w1[4] + b0*w2[4] + b1*w3[4];
  }
  float* o = out + (size_t)row * 5;
  o[0]=acc0; o[1]=acc1; o[2]=acc2; o[3]=acc3; o[4]=acc4;
}

extern "C" void kernel_launch(void* const* d_in, const int* in_sizes, int n_in,
                              void* d_out, int out_size, void* d_ws, size_t ws_size,
                              hipStream_t stream)
{
  const float* signals = (const float*)d_in[0];
  const int*   lens    = (const int*)  d_in[1];
  const float* k1w     = (const float*)d_in[2];
  const float* k1aw    = (const float*)d_in[3];
  const float* k1ab    = (const float*)d_in[4];
  const float* k2w     = (const float*)d_in[5];
  const float* k3w     = (const float*)d_in[6];
  const float* Wf      = (const float*)d_in[7];
  const float* bf      = (const float*)d_in[8];
  const float* Wb      = (const float*)d_in[9];
  const float* bb      = (const float*)d_in[10];
  const float* Wd      = (const float*)d_in[11];
  const float* bd      = (const float*)d_in[12];
  float* out = (float*)d_out;
  char* ws = (char*)d_ws;

  // Region A aliases C2 (conv phase) and the XW double buffer — disjoint lifetimes.
  size_t szC2   = (size_t)NROWS * 256 * 2;          // 33,554,432
  size_t szXWb  = 2 * XWSZ * 2;                     // 26,214,400 (2 x 13.1MB)
  size_t szA    = (szC2 > szXWb) ? szC2 : szXWb;
  size_t oA   = 0;
  size_t oE   = oA   + szA;
  size_t oFw  = oE   + (size_t)NROWS*256*2;
  size_t oBw  = oFw  + (size_t)NROWS*HH*2;
  size_t oWhK = oBw  + (size_t)NROWS*HH*2;
  size_t oWx2 = oWhK + (size_t)320000*2;            // 640,000
  size_t oK3  = oWx2 + (size_t)2*256*800*2;
  size_t oPQ  = oK3  + (size_t)256*256*2;
  size_t oBc  = oPQ  + 1536*4;
  size_t oCst = oBc  + 1600*4;
  size_t oHst = oCst + (size_t)64*HH*4;
  size_t total= oHst + (size_t)64*HH*2;
  if (ws_size < total) return;

  unsigned short* C2    = (unsigned short*)(ws + oA);
  unsigned short* XWbuf = (unsigned short*)(ws + oA);
  unsigned short* E     = (unsigned short*)(ws + oE);
  unsigned short* fwH   = (unsigned short*)(ws + oFw);
  unsigned short* bwH   = (unsigned short*)(ws + oBw);
  unsigned short* WhK   = (unsigned short*)(ws + oWhK);
  unsigned short* Wx2   = (unsigned short*)(ws + oWx2);
  unsigned short* K3h   = (unsigned short*)(ws + oK3);
  float* PQ     = (float*)(ws + oPQ);
  float* bcat   = (float*)(ws + oBc);
  float* cState = (float*)(ws + oCst);
  unsigned short* hState = (unsigned short*)(ws + oHst);

  (void)hipMemsetAsync(fwH, 0, (size_t)2*NROWS*HH*2, stream);
  pq_kernel  <<<6,     256, 0, stream>>>(k1w, k2w, PQ);
  prep_kernel<<<3113,  256, 0, stream>>>(k3w, Wf, bf, Wb, bb, K3h, Wx2, WhK, bcat);
  conv2_kernel<<<NROWS, 256, 0, stream>>>(signals, PQ, C2);
  gemm_kernel<<<1024,  256, 0, stream>>>(C2, K3h, 256, 2, 0, E, nullptr, signals, k1aw, k1ab, nullptr, 0);
  // prologue: XW for chunk 0 into buffer 0
  gemm_kernel<<<448,   256, 0, stream>>>(E, Wx2, 800, 7, 2, XWbuf, bcat, nullptr, nullptr, nullptr, lens, 0);
  for (int k = 0; k < T_LEN / TB; ++k) {
    mega_kernel<<<214, 1024, 0, stream>>>(E, Wx2, XWbuf, bcat, WhK, lens, fwH, bwH, cState, hState, k);
  }
  out_kernel <<<256,   256, 0, stream>>>(fwH, bwH, Wd, bd, out);
}

// Round 16
// 2279.429 us; speedup vs baseline: 5.5124x; 1.0297x over previous
//
#include <hip/hip_runtime.h>
#include <cstdint>

#define T_LEN 2048
#define NB    32
#define NROWS (NB*T_LEN)   // 65536
#define HH    200
#define G4    800
#define TB    128          // XW chunk granularity
#define SB    8            // step block staged in LDS
#define XWSZ  ((size_t)64 * TB * 800)   // halves per XW buffer

typedef _Float16 f16;
typedef _Float16 f16x2 __attribute__((ext_vector_type(2)));
typedef _Float16 f16x8 __attribute__((ext_vector_type(8)));
typedef float   floatx4 __attribute__((ext_vector_type(4)));

#define GLD_LDS16(g, l) __builtin_amdgcn_global_load_lds( \
    (const __attribute__((address_space(1))) void*)(g), \
    (__attribute__((address_space(3))) void*)(l), 16, 0, 0)

static __device__ __forceinline__ unsigned short f2h(float x) {
  f16 h = (f16)x; return __builtin_bit_cast(unsigned short, h);
}
static __device__ __forceinline__ float dot2f(unsigned int a, unsigned int b, float c) {
  return __builtin_amdgcn_fdot2(__builtin_bit_cast(f16x2, a),
                                __builtin_bit_cast(f16x2, b), c, false);
}
static __device__ __forceinline__ float sigm(float x) {
  return __builtin_amdgcn_rcpf(1.f + __expf(-x));
}
static __device__ __forceinline__ float tanh_fast(float x) {
  return 1.f - 2.f * __builtin_amdgcn_rcpf(__expf(2.f * x) + 1.f);
}

// ---------------- P/Q precompute: P[dt,co]=sum_ci relu(k1)k2, Q with relu(-k1)
__global__ void pq_kernel(const float* __restrict__ k1w, const float* __restrict__ k2w,
                          float* __restrict__ PQ) {
  int id = blockIdx.x * 256 + threadIdx.x;   // 1536 total
  int pq = id / 768;
  int rem = id % 768;
  int wdt = rem / 256;
  int co  = rem % 256;
  float acc = 0.f;
  for (int ci = 0; ci < 256; ++ci) {
    float k = k1w[ci];
    float kk = pq ? fmaxf(-k, 0.f) : fmaxf(k, 0.f);
    acc += kk * k2w[((size_t)wdt * 256 + ci) * 256 + co];
  }
  PQ[id] = acc;
}

// ---------------- f16 weight prep (B matrices stored TRANSPOSED: [n][k])
// K3T[co][ci] ; Wx2[dir][c][k] with permuted col c=4n+q (gate g=q*200+n) ;
// WhK: per-thread 5-way k-chunk weight records [dir][s<5][n<200][4 gates][40 halves] ;
// bcat permuted, f-gate +1 folded.
__global__ void prep_kernel(const float* __restrict__ k3w,
                            const float* __restrict__ Wf, const float* __restrict__ bfv,
                            const float* __restrict__ Wb, const float* __restrict__ bbv,
                            unsigned short* __restrict__ K3h, unsigned short* __restrict__ Wx2,
                            unsigned short* __restrict__ WhK, float* __restrict__ bcat) {
  int id = blockIdx.x * 256 + threadIdx.x;
  if (id < 65536) {                      // K3T[co*256+ci] = k3w[ci*256+co]
    K3h[id] = f2h(k3w[(id & 255) * 256 + (id >> 8)]);
    return;
  }
  id -= 65536;
  if (id < 409600) {                     // Wx2[dir][c<800][k<256]
    int dirv = id / 204800;
    int r = id % 204800;
    int c = r >> 8, k = r & 255;
    int n = c >> 2, q = c & 3;
    int g = q * 200 + n;
    const float* W = dirv ? Wb : Wf;
    Wx2[id] = f2h(W[k * 800 + g]);
    return;
  }
  id -= 409600;
  if (id < 320000) {                     // WhK halves: 2*5*200*160
    int rec = id / 160;
    int m   = id % 160;
    int g   = m / 40, j = m % 40;
    int n   = rec % 200;
    int t2  = rec / 200;                 // 0..9
    int s   = t2 % 5, dirv = t2 / 5;
    int k   = s * 40 + j;
    const float* W = dirv ? Wb : Wf;
    WhK[id] = f2h(W[(256 + k) * 800 + (g * 200 + n)]);
    return;
  }
  id -= 320000;
  if (id < 1600) {                       // bcat[dir*800 + c] with same perm; +1 on f gate
    int dirv = id / 800;
    int c = id % 800;
    int n = c >> 2, q = c & 3;
    int g = q * 200 + n;
    bcat[id] = (dirv ? bbv : bfv)[g] + (q == 2 ? 1.f : 0.f);
  }
}

// ---------------- conv2 via rank-1 collapse (6 FMA/elem)
__global__ void conv2_kernel(const float* __restrict__ s, const float* __restrict__ PQ,
                             unsigned short* __restrict__ C2) {
  int row = blockIdx.x;
  int co  = threadIdx.x;
  int t = row & (T_LEN - 1);
  float s0 = s[row];
  float sm = (t > 0)         ? s[row - 1] : 0.f;
  float sp = (t < T_LEN - 1) ? s[row + 1] : 0.f;
  const float* P = PQ;
  const float* Q = PQ + 768;
  float acc = 0.f;
  float a, m;
  a = fmaxf(sm, 0.f); m = fmaxf(-sm, 0.f);
  acc += a * P[0*256+co] + m * Q[0*256+co];
  a = fmaxf(s0, 0.f); m = fmaxf(-s0, 0.f);
  acc += a * P[1*256+co] + m * Q[1*256+co];
  a = fmaxf(sp, 0.f); m = fmaxf(-sp, 0.f);
  acc += a * P[2*256+co] + m * Q[2*256+co];
  C2[(size_t)row * 256 + co] = f2h(fmaxf(acc, 0.f));
}

// ---------------- MFMA GEMM, K=256 fixed. B given TRANSPOSED [n][256].
// mode 0: direct rows; out = relu(acc) + relu(s*k1aw+k1ab)   (conv3+conv1a -> enc)
// mode 2: gathered rows (chain/time-chunk, TB=128); out = acc + bcat[dir*800+col]
__global__ __launch_bounds__(256, 2) void gemm_kernel(
    const unsigned short* __restrict__ Ag, const unsigned short* __restrict__ Bg0,
    int N, int ntiles, int mode,
    unsigned short* __restrict__ Outp,
    const float* __restrict__ bias, const float* __restrict__ Sg,
    const float* __restrict__ k1aw, const float* __restrict__ k1ab,
    const int* __restrict__ lens, int t0)
{
  __shared__ __align__(16) unsigned short Bl[128*128]; // [n][k-phase], xor-swizzled 16B chunks
  __shared__ __align__(16) unsigned short Al[128*40];  // [m][k32], pad 40 halves
  __shared__ int rowsrc[128];
  int tid = threadIdx.x;
  int tm = blockIdx.x / ntiles, tn = blockIdx.x % ntiles;
  int col0 = tn * 128;
  int lane = tid & 63, wv = tid >> 6;
  int quad = lane >> 4, l16 = lane & 15;
  int wrow = (wv & 1) * 64, wcol = (wv >> 1) * 64;

  int dirv = 0;
  if (mode == 2) dirv = tm >> 5;   // TB=128: row-tile == chain ; dir = chain>>5
  const unsigned short* Bg = Bg0 + (size_t)dirv * 204800;

  if (tid < 128) {
    int r;
    if (mode == 2) {
      int m = tm * 128 + tid;
      int ch = m >> 7;              // TB=128
      int ls = m & 127;
      int b = ch & 31, dd = ch >> 5;
      int L = lens[b]; L = (L < 0) ? 0 : ((L > T_LEN) ? T_LEN : L);
      int t = t0 + ls;
      int src = dd ? (L - 1 - t) : t;
      src = (src < 0) ? 0 : ((src > T_LEN - 1) ? (T_LEN - 1) : src);
      r = b * T_LEN + src;
    } else {
      r = tm * 128 + tid;
    }
    rowsrc[tid] = r;
  }

  floatx4 acc[16];
  #pragma unroll
  for (int i = 0; i < 16; ++i) acc[i] = (floatx4){0.f,0.f,0.f,0.f};

  for (int ph = 0; ph < 2; ++ph) {
    __syncthreads();
    // stage B half-panel from BT: rows n in [col0,col0+128), k in [ph*128, +128)
    #pragma unroll
    for (int it = 0; it < 8; ++it) {
      int idx = it * 256 + tid;             // 2048 b128 chunks
      int n  = idx >> 4;                    // 0..127 local col
      int k8 = idx & 15;                    // 16B chunk within phase
      int nn = col0 + n;
      uint4 v = (uint4){0u,0u,0u,0u};
      if (nn < N) v = *(const uint4*)(Bg + (size_t)nn * 256 + ph * 128 + k8 * 8);
      *(uint4*)(&Bl[n * 128 + ((k8 ^ (n & 7)) * 8)]) = v;
    }
    for (int kb2 = 0; kb2 < 4; ++kb2) {
      int kb = ph * 4 + kb2;
      __syncthreads();
      #pragma unroll
      for (int i = 0; i < 2; ++i) {
        int c2 = i * 256 + tid;
        int r = c2 >> 2, kc = (c2 & 3) * 8;
        uint4 v = *(const uint4*)(Ag + (size_t)rowsrc[r] * 256 + kb * 32 + kc);
        *(uint4*)(&Al[r * 40 + kc]) = v;
      }
      __syncthreads();
      f16x8 af[4], bfr[4];
      #pragma unroll
      for (int mt = 0; mt < 4; ++mt)
        af[mt] = *(const f16x8*)(&Al[(wrow + mt*16 + l16) * 40 + quad * 8]);
      #pragma unroll
      for (int nt = 0; nt < 4; ++nt) {
        int nl = wcol + nt*16 + l16;
        int c = kb2 * 4 + quad;
        bfr[nt] = *(const f16x8*)(&Bl[nl * 128 + ((c ^ (nl & 7)) * 8)]);
      }
      #pragma unroll
      for (int mt = 0; mt < 4; ++mt)
        #pragma unroll
        for (int nt = 0; nt < 4; ++nt)
          acc[mt*4+nt] = __builtin_amdgcn_mfma_f32_16x16x32_f16(af[mt], bfr[nt], acc[mt*4+nt], 0, 0, 0);
    }
  }
  #pragma unroll
  for (int mt = 0; mt < 4; ++mt) {
    #pragma unroll
    for (int nt = 0; nt < 4; ++nt) {
      floatx4 v = acc[mt*4+nt];
      int col = col0 + wcol + nt*16 + l16;
      if (col < N) {
        #pragma unroll
        for (int r = 0; r < 4; ++r) {
          int row = tm * 128 + wrow + mt*16 + quad*4 + r;
          float x = v[r];
          float o;
          if (mode == 0) {
            float sv = Sg[row];
            float a1 = sv * k1aw[col] + k1ab[col];
            o = fmaxf(x, 0.f) + fmaxf(a1, 0.f);
          } else {
            o = x + bias[dirv * 800 + col];
          }
          Outp[(size_t)row * N + col] = f2h(o);
        }
      }
    }
  }
}

// ---------------- MEGA kernel: lstm(chunks k..k+nc-1) || gemm(chunks k+nc..k+2nc-1).
// Grid 214 x 1024. Blocks 0-63: R15-verified lstm, now looping nc chunks with state,
// weights and himg parity persisting in-register across the pair (kills the per-launch
// prologue reload). Blocks 64-213: mode-2 XW GEMM for the next nc chunks into a
// (nc*2)-deep buffer ring (kk & bmask): read-set {k..k+nc-1} and write-set
// {k+nc..k+2nc-1} are disjoint mod (2nc). nc=1/bmask=1 reproduces R15 exactly
// (host falls back to it when ws_size can't fit the 4-buffer ring).
__global__ __launch_bounds__(1024, 4)
void mega_kernel(
    const unsigned short* __restrict__ Eg,     // enc rows [NROWS][256]
    const unsigned short* __restrict__ Wx2,    // gemm B (transposed, per dir)
    unsigned short* __restrict__ XWbuf,        // buffer ring base
    const float* __restrict__ bcat,
    const unsigned short* __restrict__ WhK,    // lstm weight records
    const int* __restrict__ lens,
    unsigned short* __restrict__ fwH, unsigned short* __restrict__ bwH,
    float* __restrict__ cState, unsigned short* __restrict__ hState,
    int k, int nc, int bmask)
{
  __shared__ __align__(16) unsigned short xw_lds[2][SB*800]; // 25.6 KB (lstm)
  __shared__ __align__(16) unsigned short hist[SB*200];      // 3.2 KB  (lstm)
  __shared__ __align__(16) unsigned short himg[2][200];      // 0.8 KB  (lstm)
  __shared__ __align__(16) floatx4 zp[800];                  // 12.8 KB (lstm)
  __shared__ __align__(16) unsigned short Bl[128*128];       // 32 KB   (gemm)
  __shared__ __align__(16) unsigned short Al[128*40];        // 10 KB   (gemm)
  __shared__ int rowsrc[128];                                //          (gemm)

  int tid = threadIdx.x;

  if (blockIdx.x < 64) {
    // ================= LSTM part =================
    int ch  = blockIdx.x;
    int dir = ch >> 5;
    int b   = ch & 31;
    int L = lens[b];
    L = (L < 0) ? 0 : ((L > T_LEN) ? T_LEN : L);
    bool worker = tid < 1000;
    int s = tid / 200;
    int n = tid - s * 200;
    int t0 = k * TB;

    if (tid < 200) ((unsigned int*)himg)[tid] = 0u;

    float c = 0.f;
    unsigned short last_h = 0;
    if (tid < 200 && t0 > 0) {
      c = cState[ch * HH + tid];
      last_h = hState[ch * HH + tid];
    }
    __syncthreads();
    if (tid < 200 && t0 > 0) himg[0][tid] = last_h;

    unsigned int w[80];
    if (worker) {
      const uint4* wp = (const uint4*)(WhK + ((size_t)((dir * 5 + s) * 200 + n)) * 160);
      #pragma unroll
      for (int r = 0; r < 20; ++r) {
        uint4 v = wp[r];
        w[4*r+0] = v.x; w[4*r+1] = v.y; w[4*r+2] = v.z; w[4*r+3] = v.w;
      }
      #pragma unroll
      for (int r = 0; r < 80; ++r)
        asm volatile("" : "+v"(w[r]));
    }

    unsigned short* Hd = dir ? bwH : fwH;
    int cur = 0;
    int prev_tb = -1, prev_cnt = 0;

    for (int kk = k; kk < k + nc; ++kk) {
      int t0c = kk * TB;
      int tend = t0c + TB; if (tend > L) tend = L;
      const unsigned short* XWc = XWbuf + (size_t)(kk & bmask) * XWSZ + ((size_t)ch * TB) * 800;

      if (t0c < tend && tid < 800)
        GLD_LDS16(XWc + (size_t)tid * 8, &xw_lds[0][tid * 8]);
      __syncthreads();   // chunk-0 DMA drained; h/himg visible

      int buf = 0;
      for (int tb = t0c; tb < tend; tb += SB) {
        int cnt = tend - tb; if (cnt > SB) cnt = SB;
        for (int sl = 0; sl < cnt; ++sl) {
          if (sl == 0) {
            int ntb = tb + SB;
            if ((ntb - t0c) < TB && tid < 800) {
              const unsigned short* src = XWc + (size_t)(ntb - t0c) * 800;
              GLD_LDS16(src + (size_t)tid * 8, &xw_lds[buf ^ 1][tid * 8]);
            }
            if (prev_tb >= 0) {
              int pcnt = prev_cnt;
              if (tid < pcnt * 25) {
                int srow = dir ? (pcnt - 1 - tid / 25) : (tid / 25);
                uint4 v = *(const uint4*)&hist[srow*200 + (tid % 25)*8];
                size_t base = dir ? ((size_t)(b*T_LEN + (L - prev_tb - pcnt)))*HH
                                  : ((size_t)(b*T_LEN + prev_tb))*HH;
                *(uint4*)(Hd + base + (size_t)tid*8) = v;
              }
            }
          }
          float a0 = 0.f, a1 = 0.f, a2 = 0.f, a3 = 0.f;
          if (worker) {
            const uint4* hp = (const uint4*)(&himg[cur][s * 40]);
            #pragma unroll
            for (int r = 0; r < 5; ++r) {
              uint4 hv = hp[r];
              int d = r * 4;
              a0 = dot2f(hv.x, w[d],      a0); a1 = dot2f(hv.x, w[20 + d], a1);
              a2 = dot2f(hv.x, w[40 + d], a2); a3 = dot2f(hv.x, w[60 + d], a3);
              a0 = dot2f(hv.y, w[d + 1],  a0); a1 = dot2f(hv.y, w[21 + d], a1);
              a2 = dot2f(hv.y, w[41 + d], a2); a3 = dot2f(hv.y, w[61 + d], a3);
              a0 = dot2f(hv.z, w[d + 2],  a0); a1 = dot2f(hv.z, w[22 + d], a1);
              a2 = dot2f(hv.z, w[42 + d], a2); a3 = dot2f(hv.z, w[62 + d], a3);
              a0 = dot2f(hv.w, w[d + 3],  a0); a1 = dot2f(hv.w, w[23 + d], a1);
              a2 = dot2f(hv.w, w[43 + d], a2); a3 = dot2f(hv.w, w[63 + d], a3);
            }
            if (s != 0) {
              floatx4 z; z[0] = a0; z[1] = a1; z[2] = a2; z[3] = a3;
              zp[(s - 1) * 200 + n] = z;
            }
          }
          __syncthreads();
          if (tid < 200) {
            floatx4 p0 = zp[tid], p1 = zp[200 + tid], p2 = zp[400 + tid], p3 = zp[600 + tid];
            uint2 xv = *(const uint2*)&xw_lds[buf][sl*800 + 4*tid];
            f16x2 xa = __builtin_bit_cast(f16x2, xv.x);
            f16x2 xb = __builtin_bit_cast(f16x2, xv.y);
            float zi = a0 + p0[0] + p1[0] + p2[0] + p3[0] + (float)xa[0];
            float zj = a1 + p0[1] + p1[1] + p2[1] + p3[1] + (float)xa[1];
            float zf = a2 + p0[2] + p1[2] + p2[2] + p3[2] + (float)xb[0];
            float zo = a3 + p0[3] + p1[3] + p2[3] + p3[3] + (float)xb[1];
            c = c * sigm(zf) + sigm(zi) * tanh_fast(zj);
            float h = tanh_fast(c) * sigm(zo);
            unsigned short hh = f2h(h);
            last_h = hh;
            himg[cur ^ 1][tid] = hh;
            hist[sl*200 + tid] = hh;
          }
          cur ^= 1;
          __syncthreads();
        }
        prev_tb = tb; prev_cnt = cnt; buf ^= 1;
      }
    }
    // final flush + state save
    if (prev_tb >= 0) {
      int pcnt = prev_cnt;
      if (tid < pcnt * 25) {
        int srow = dir ? (pcnt - 1 - tid / 25) : (tid / 25);
        uint4 v = *(const uint4*)&hist[srow*200 + (tid % 25)*8];
        size_t base = dir ? ((size_t)(b*T_LEN + (L - prev_tb - pcnt)))*HH
                          : ((size_t)(b*T_LEN + prev_tb))*HH;
        *(uint4*)(Hd + base + (size_t)tid*8) = v;
      }
    }
    if (tid < 200) {
      cState[ch * HH + tid] = c;
      hState[ch * HH + tid] = last_h;
    }
    return;
  }

  // ================= GEMM part: chunks k+nc..k+2nc-1 =================
  int lane = tid & 63, wv = tid >> 6;
  int quad = lane >> 4, l16 = lane & 15;
  int wrow = (wv & 1) * 64, wcol = (wv >> 1) * 64;

  for (int task = blockIdx.x - 64; task < 448 * nc; task += 150) {
    int ct  = task / 448;
    int rem = task - ct * 448;
    int kk  = k + nc + ct;
    int tgem = kk * TB;
    if (tgem >= T_LEN) break;           // block-uniform; later tasks also dead
    unsigned short* Outp = XWbuf + (size_t)(kk & bmask) * XWSZ;
    int tm = rem / 7, tn = rem % 7;
    int col0 = tn * 128;
    int dirv = tm >> 5;                 // chain == tm at TB=128
    const unsigned short* Bg = Wx2 + (size_t)dirv * 204800;

    __syncthreads();   // orders prior task's LDS reads before rewrite
    if (tid < 128) {
      int m = tm * 128 + tid;
      int chn = m >> 7;
      int ls = m & 127;
      int bb = chn & 31, dd = chn >> 5;
      int L = lens[bb]; L = (L < 0) ? 0 : ((L > T_LEN) ? T_LEN : L);
      int t = tgem + ls;
      int src = dd ? (L - 1 - t) : t;
      src = (src < 0) ? 0 : ((src > T_LEN - 1) ? (T_LEN - 1) : src);
      rowsrc[tid] = bb * T_LEN + src;
    }

    floatx4 acc[16];
    #pragma unroll
    for (int i = 0; i < 16; ++i) acc[i] = (floatx4){0.f,0.f,0.f,0.f};

    for (int ph = 0; ph < 2; ++ph) {
      __syncthreads();
      if (tid < 256) {
        #pragma unroll
        for (int it = 0; it < 8; ++it) {
          int idx = it * 256 + tid;
          int nl = idx >> 4;
          int k8 = idx & 15;
          int nn = col0 + nl;
          uint4 v = (uint4){0u,0u,0u,0u};
          if (nn < 800) v = *(const uint4*)(Bg + (size_t)nn * 256 + ph * 128 + k8 * 8);
          *(uint4*)(&Bl[nl * 128 + ((k8 ^ (nl & 7)) * 8)]) = v;
        }
      }
      for (int kb2 = 0; kb2 < 4; ++kb2) {
        int kb = ph * 4 + kb2;
        __syncthreads();
        if (tid < 256) {
          #pragma unroll
          for (int i = 0; i < 2; ++i) {
            int c2 = i * 256 + tid;
            int r = c2 >> 2, kc = (c2 & 3) * 8;
            uint4 v = *(const uint4*)(Eg + (size_t)rowsrc[r] * 256 + kb * 32 + kc);
            *(uint4*)(&Al[r * 40 + kc]) = v;
          }
        }
        __syncthreads();
        if (tid < 256) {
          f16x8 af[4], bfr[4];
          #pragma unroll
          for (int mt = 0; mt < 4; ++mt)
            af[mt] = *(const f16x8*)(&Al[(wrow + mt*16 + l16) * 40 + quad * 8]);
          #pragma unroll
          for (int nt = 0; nt < 4; ++nt) {
            int nl = wcol + nt*16 + l16;
            int cx = kb2 * 4 + quad;
            bfr[nt] = *(const f16x8*)(&Bl[nl * 128 + ((cx ^ (nl & 7)) * 8)]);
          }
          #pragma unroll
          for (int mt = 0; mt < 4; ++mt)
            #pragma unroll
            for (int nt = 0; nt < 4; ++nt)
              acc[mt*4+nt] = __builtin_amdgcn_mfma_f32_16x16x32_f16(af[mt], bfr[nt], acc[mt*4+nt], 0, 0, 0);
        }
      }
    }
    if (tid < 256) {
      #pragma unroll
      for (int mt = 0; mt < 4; ++mt) {
        #pragma unroll
        for (int nt = 0; nt < 4; ++nt) {
          floatx4 v = acc[mt*4+nt];
          int col = col0 + wcol + nt*16 + l16;
          if (col < 800) {
            #pragma unroll
            for (int r = 0; r < 4; ++r) {
              int row = tm * 128 + wrow + mt*16 + quad*4 + r;
              Outp[(size_t)row * 800 + col] = f2h(v[r] + bcat[dirv * 800 + col]);
            }
          }
        }
      }
    }
  }
}

// ---------------- logits = [fwH|bwH] @ Wd + bd
__global__ __launch_bounds__(256) void out_kernel(
    const unsigned short* __restrict__ fwH, const unsigned short* __restrict__ bwH,
    const float* __restrict__ Wd, const float* __restrict__ bd, float* __restrict__ out)
{
  __shared__ float wd[2000];
  int tid = threadIdx.x;
  for (int i = tid; i < 2000; i += 256) wd[i] = Wd[i];
  __syncthreads();
  int row = blockIdx.x * 256 + tid;
  float acc0 = bd[0], acc1 = bd[1], acc2 = bd[2], acc3 = bd[3], acc4 = bd[4];
  const unsigned int* fu = (const unsigned int*)(fwH + (size_t)row * HH);
  const unsigned int* bu = (const unsigned int*)(bwH + (size_t)row * HH);
  #pragma unroll 4
  for (int i = 0; i < 100; ++i) {
    f16x2 pf = __builtin_bit_cast(f16x2, fu[i]);
    f16x2 pb = __builtin_bit_cast(f16x2, bu[i]);
    int k = 2 * i;
    float f0 = (float)pf[0], f1 = (float)pf[1];
    float b0 = (float)pb[0], b1 = (float)pb[1];
    const float* w0 = &wd[k*5];
    const float* w1 = &wd[(k+1)*5];
    const float* w2 = &wd[(200+k)*5];
    const float* w3 = &wd[(201+k)*5];
    acc0 += f0*w0[0] + f1*w1[0] + b0*w2[0] + b1*w3[0];
    acc1 += f0*w0[1] + f1*w1[1] + b0*w2[1] + b1*w3[1];
    acc2 += f0*w0[2] + f1*w1[2] + b0*w2[2] + b1*w3[2];
    acc3 += f0*w0[3] + f1*w1[3] + b0*w2[3] + b1*w3[3];
    acc4 += f0*w0[4] + f1*w1[4] + b0*w2[4] + b1*w3[4];
  }
  float* o = out + (size_t)row * 5;
  o[0]=acc0; o[1]=acc1; o[2]=acc2; o[3]=acc3; o[4]=acc4;
}

extern "C" void kernel_launch(void* const* d_in, const int* in_sizes, int n_in,
                              void* d_out, int out_size, void* d_ws, size_t ws_size,
                              hipStream_t stream)
{
  const float* signals = (const float*)d_in[0];
  const int*   lens    = (const int*)  d_in[1];
  const float* k1w     = (const float*)d_in[2];
  const float* k1aw    = (const float*)d_in[3];
  const float* k1ab    = (const float*)d_in[4];
  const float* k2w     = (const float*)d_in[5];
  const float* k3w     = (const float*)d_in[6];
  const float* Wf      = (const float*)d_in[7];
  const float* bf      = (const float*)d_in[8];
  const float* Wb      = (const float*)d_in[9];
  const float* bb      = (const float*)d_in[10];
  const float* Wd      = (const float*)d_in[11];
  const float* bd      = (const float*)d_in[12];
  float* out = (float*)d_out;
  char* ws = (char*)d_ws;

  size_t szC2 = (size_t)NROWS * 256 * 2;            // 33,554,432
  size_t XWbytes = XWSZ * 2;                        // 13,107,200 per buffer

  // choose ring depth: 4 buffers (nc=2) if workspace allows, else 2 (nc=1, ==R15)
  int nbuf = 4;
  size_t oA, oE, oFw, oBw, oWhK, oWx2, oK3, oPQ, oBc, oCst, oHst, total;
  for (;;) {
    size_t szXWb = (size_t)nbuf * XWbytes;
    size_t szA   = (szC2 > szXWb) ? szC2 : szXWb;
    oA   = 0;
    oE   = oA   + szA;
    oFw  = oE   + (size_t)NROWS*256*2;
    oBw  = oFw  + (size_t)NROWS*HH*2;
    oWhK = oBw  + (size_t)NROWS*HH*2;
    oWx2 = oWhK + (size_t)320000*2;
    oK3  = oWx2 + (size_t)2*256*800*2;
    oPQ  = oK3  + (size_t)256*256*2;
    oBc  = oPQ  + 1536*4;
    oCst = oBc  + 1600*4;
    oHst = oCst + (size_t)64*HH*4;
    total= oHst + (size_t)64*HH*2;
    if (ws_size >= total) break;
    if (nbuf == 2) return;
    nbuf = 2;
  }
  int nc = nbuf / 2, bmask = nbuf - 1;

  unsigned short* C2    = (unsigned short*)(ws + oA);
  unsigned short* XWbuf = (unsigned short*)(ws + oA);
  unsigned short* E     = (unsigned short*)(ws + oE);
  unsigned short* fwH   = (unsigned short*)(ws + oFw);
  unsigned short* bwH   = (unsigned short*)(ws + oBw);
  unsigned short* WhK   = (unsigned short*)(ws + oWhK);
  unsigned short* Wx2   = (unsigned short*)(ws + oWx2);
  unsigned short* K3h   = (unsigned short*)(ws + oK3);
  float* PQ     = (float*)(ws + oPQ);
  float* bcat   = (float*)(ws + oBc);
  float* cState = (float*)(ws + oCst);
  unsigned short* hState = (unsigned short*)(ws + oHst);

  (void)hipMemsetAsync(fwH, 0, (size_t)2*NROWS*HH*2, stream);
  pq_kernel  <<<6,     256, 0, stream>>>(k1w, k2w, PQ);
  prep_kernel<<<3113,  256, 0, stream>>>(k3w, Wf, bf, Wb, bb, K3h, Wx2, WhK, bcat);
  conv2_kernel<<<NROWS, 256, 0, stream>>>(signals, PQ, C2);
  gemm_kernel<<<1024,  256, 0, stream>>>(C2, K3h, 256, 2, 0, E, nullptr, signals, k1aw, k1ab, nullptr, 0);
  // prologue: XW for chunks 0..nc-1 into buffers 0..nc-1
  for (int j = 0; j < nc; ++j)
    gemm_kernel<<<448, 256, 0, stream>>>(E, Wx2, 800, 7, 2, XWbuf + (size_t)j * XWSZ,
                                         bcat, nullptr, nullptr, nullptr, lens, j * TB);
  for (int k = 0; k < T_LEN / TB; k += nc) {
    mega_kernel<<<214, 1024, 0, stream>>>(E, Wx2, XWbuf, bcat, WhK, lens,
                                          fwH, bwH, cState, hState, k, nc, bmask);
  }
  out_kernel <<<256,   256, 0, stream>>>(fwH, bwH, Wd, bd, out);
}